// Round 7
// baseline (146.409 us; speedup 1.0000x reference)
//
#include <hip/hip_runtime.h>
#include <cstdint>

// ---------------- problem constants ----------------
// QG=8, N=1024, DIM=512, H=8, D=64; rows/tensor=8192; HQ=64
// Fragment layout for MFMA operands ([outdim-blk][kchunk][i15][q4][8] u16):
//   off = rowblk*8192 + S*512 + i15*32 + q4*8   (S = k>>5, q4 = (k>>3)&3)

typedef unsigned short u16;
typedef unsigned int u32;
typedef __attribute__((ext_vector_type(8))) unsigned short u16x8;
typedef __attribute__((ext_vector_type(4))) unsigned short u16x4;
typedef __attribute__((ext_vector_type(8))) short short8;
typedef __attribute__((ext_vector_type(4))) float floatx4;

// ---------------- workspace layout (float offsets) ----------------
#define WS_XBF     0LL          // bf16 frag [1536 rowblk][16 S][512]  (q,k,v stacked)
#define WS_OATT    4194304LL    // bf16 frag [512 rowblk][16 S][512] (aliases XBF tail)
#define WS_WPT     6291456LL    // bf16 W'T [512][512]
#define WS_WOT     6422528LL    // bf16 w_outT [512][512]
#define WS_U       6553600LL    // f32 [512]  g@W_in
#define WS_CB      6554112LL    // f32 [512]  b@W_in
#define WS_LNST    6554624LL    // f32 [24576][2] (mu, rsigma)
#define WS_FQ      6603776LL    // bf16 [64 hq][1024 n][64 d] row-major
#define WS_FKTS    8700928LL    // bf16 frag per hq: [4 eblk][32 kb][16][4][8]
#define WS_FKTC    10798080LL   // bf16 frag (centered)
#define WS_FVT     12895232LL   // bf16 frag
#define WS_INVNQ   14992384LL   // f32 [64][1024]
#define WS_INVNK   15057920LL   // (written, unused downstream)
#define WS_QMEAN   15123456LL
#define WS_KMEAN   15188992LL   // (written, unused downstream)
#define WS_COLP    15254528LL   // f32 [2][64][8][64][2] (sum, sumsq)
#define WS_WGATE   15385600LL   // f32 [8] (+pad)
#define WS_WTF32   15385664LL   // f32 WT [512][512] (prep-phase only)
#define WS_GSUM    15385664LL   // f32 [2][8][64][2] (gatered->gate only)
#define WS_MTB     15385664LL   // bf16 M^T [64 hq][64 d][64 e] (mc->apply)
#define WS_CTB     15516736LL   // bf16 C^T
#define WS_COLC    15647808LL   // f32 [64][64] colsum of C
// end = 15651904 floats = 62.6 MB

__device__ __forceinline__ float wsum(float v) {
#pragma unroll
    for (int m = 32; m; m >>= 1) v += __shfl_xor(v, m, 64);
    return v;
}
__device__ __forceinline__ u16 f2bf(float f) {
    u32 u = __float_as_uint(f);
    u32 r = u + 0x7fffu + ((u >> 16) & 1u);
    return (u16)(r >> 16);
}

// ---------------- K0: LN row stats over DIM=512 + bf16 frag-layout copy ----
__global__ __launch_bounds__(256) void k_lnstats(
    const float* __restrict__ q, const float* __restrict__ k,
    const float* __restrict__ v, float* __restrict__ ws) {
    int wid = threadIdx.x >> 6, lane = threadIdx.x & 63;
    int row = blockIdx.x * 4 + wid;            // 0..24575
    int t = row >> 13, r = row & 8191;
    const float* src = (t == 0) ? q : ((t == 1) ? k : v);
    const float4* p = (const float4*)(src + (size_t)r * 512) + lane * 2;
    float4 a = p[0], b = p[1];
    u16x8 o;
    o[0] = f2bf(a.x); o[1] = f2bf(a.y); o[2] = f2bf(a.z); o[3] = f2bf(a.w);
    o[4] = f2bf(b.x); o[5] = f2bf(b.y); o[6] = f2bf(b.z); o[7] = f2bf(b.w);
    // frag layout: k = lane*8 -> S = lane>>2, q4 = lane&3
    *(u16x8*)((u16*)(ws + WS_XBF) + (size_t)(row >> 4) * 8192 +
              (lane >> 2) * 512 + (row & 15) * 32 + (lane & 3) * 8) = o;
    float s = a.x + a.y + a.z + a.w + b.x + b.y + b.z + b.w;
    float ss = a.x * a.x + a.y * a.y + a.z * a.z + a.w * a.w +
               b.x * b.x + b.y * b.y + b.z * b.z + b.w * b.w;
    s = wsum(s); ss = wsum(ss);
    if (lane == 0) {
        float mu = s * (1.f / 512.f);
        float var = ss * (1.f / 512.f) - mu * mu;
        ws[WS_LNST + (size_t)row * 2] = mu;
        ws[WS_LNST + (size_t)row * 2 + 1] = rsqrtf(var + 1e-5f);
    }
}

// ---------------- prep: transposed (scaled) bf16 weights ----------------
template <int SCALE>
__global__ __launch_bounds__(256) void k_prep_t(
    const float* __restrict__ W, const float* __restrict__ g,
    u16* __restrict__ Tb, float* __restrict__ Tf) {
    __shared__ float tile[64][65];
    int k0 = blockIdx.x * 64, j0 = blockIdx.y * 64;
    int tid = threadIdx.x;
    int c = (tid & 15) * 4, r0 = tid >> 4;
#pragma unroll
    for (int p = 0; p < 4; p++) {
        int r = r0 + p * 16;
        *(float4*)&tile[r][c] = *(const float4*)(W + (size_t)(k0 + r) * 512 + j0 + c);
    }
    __syncthreads();
    int kc = (tid & 15) * 4, jr0 = tid >> 4;
#pragma unroll
    for (int p = 0; p < 4; p++) {
        int jr = jr0 + p * 16;
        float v0 = tile[kc + 0][jr], v1 = tile[kc + 1][jr];
        float v2 = tile[kc + 2][jr], v3 = tile[kc + 3][jr];
        if (SCALE) {
            *(float4*)(Tf + (size_t)(j0 + jr) * 512 + k0 + kc) = (float4){v0, v1, v2, v3};
            v0 *= g[k0 + kc + 0]; v1 *= g[k0 + kc + 1];
            v2 *= g[k0 + kc + 2]; v3 *= g[k0 + kc + 3];
        }
        u16x4 ob = {f2bf(v0), f2bf(v1), f2bf(v2), f2bf(v3)};
        *(u16x4*)(Tb + (size_t)(j0 + jr) * 512 + k0 + kc) = ob;
    }
}

// ---------------- prep2: u = g@W, cb = b@W (from WT f32) ----------------
__global__ __launch_bounds__(256) void k_prep_u(
    const float* __restrict__ g, const float* __restrict__ b, float* __restrict__ ws) {
    int wid = threadIdx.x >> 6, lane = threadIdx.x & 63;
    int j = blockIdx.x * 4 + wid;              // 0..511
    const float* Tf = ws + WS_WTF32 + (size_t)j * 512;
    float su = 0.f, sc = 0.f;
#pragma unroll
    for (int m = 0; m < 8; m++) {
        int k = lane * 8 + m;
        float w = Tf[k];
        su += g[k] * w; sc += b[k] * w;
    }
    su = wsum(su); sc = wsum(sc);
    if (lane == 0) { ws[WS_U + j] = su; ws[WS_CB + j] = sc; }
}

// ---------------- bf16 MFMA GEMM, barrier-free K loop ----------------------
// B panel (128 cols x 256 k) resident in LDS (XOR-swizzled), 2 K-phases.
// A-frags loaded per-wave direct from fragment-layout global (coalesced 1KB).
// Wave grid 2(M)x4(N); wave tile 64x32 -> 4x2 fragments, 8 MFMA/K-step.
// MODE 0 (proj): epilogue f = rs*acc - rs*mu*u + cb; writes FQ row-major (t=0),
//   FKTs/FKTc frag (t=1, inv/mean folded), FVT frag (t=2) + stats/COLP.
// MODE 1 (out): +bias, f32 row-major.  CPX = gridblocks/8 (XCD swizzle).
template <int MODE, int CPX>
__global__ __launch_bounds__(512, 1) void k_gemm(
    const u16* __restrict__ A, const u16* __restrict__ B,
    float* __restrict__ ws, float* __restrict__ out, const float* __restrict__ bias) {
    __shared__ char smem[65536];               // B panel; epilogue scratch after
    int tid = threadIdx.x;
    int wid = tid >> 6, lane = tid & 63;
    int i15 = lane & 15, q4 = lane >> 4;
    int wm = wid >> 2, wn = wid & 3;
    int flat = blockIdx.x + (blockIdx.y << 2);
    int swz = (flat & 7) * CPX + (flat >> 3);
    int c0 = (swz & 3) * 128, m0 = (swz >> 2) * 128;

    floatx4 acc[4][2];
#pragma unroll
    for (int i = 0; i < 4; i++)
#pragma unroll
        for (int j = 0; j < 2; j++) acc[i][j] = (floatx4){0.f, 0.f, 0.f, 0.f};

    // panel: lds[col][slot16B] = B[c0+col][kp*256 + (slot^(col&7))*8 ..]
    auto loadpanel = [&](int kp) {
#pragma unroll
        for (int i = 0; i < 8; i++) {
            int p = wid * 8192 + i * 1024 + lane * 16;   // dest byte (linear)
            int col = p >> 9, slot = (p >> 4) & 31;
            const u16* src = B + (size_t)(c0 + col) * 512 + kp * 256 +
                             ((slot ^ (col & 7)) * 8);
            __builtin_amdgcn_global_load_lds(
                (const __attribute__((address_space(1))) void*)src,
                (__attribute__((address_space(3))) void*)(smem + p), 16, 0, 0);
        }
    };
    int arb = (m0 >> 4) + wm * 4;              // A rowblk base for this wave

    auto kstep = [&](int ks) {
        short8 a[4], b[2];
#pragma unroll
        for (int f = 0; f < 4; f++)
            a[f] = *(const short8*)(A + (size_t)(arb + f) * 8192 + ks * 512 +
                                    i15 * 32 + q4 * 8);
#pragma unroll
        for (int f = 0; f < 2; f++) {
            int col = wn * 32 + f * 16 + i15;
            int c16 = (ks & 7) * 4 + q4;
            b[f] = *(const short8*)(smem + col * 512 + ((c16 ^ (col & 7)) << 4));
        }
#pragma unroll
        for (int fm = 0; fm < 4; fm++)
#pragma unroll
            for (int fn = 0; fn < 2; fn++)
                acc[fm][fn] = __builtin_amdgcn_mfma_f32_16x16x32_bf16(
                    a[fm], b[fn], acc[fm][fn], 0, 0, 0);
    };

    loadpanel(0);
    __syncthreads();
#pragma unroll
    for (int ks = 0; ks < 8; ks++) kstep(ks);
    __syncthreads();
    loadpanel(1);
    __syncthreads();
#pragma unroll
    for (int ks = 8; ks < 16; ks++) kstep(ks);

    if constexpr (MODE == 1) {
#pragma unroll
        for (int fm = 0; fm < 4; fm++)
#pragma unroll
            for (int reg = 0; reg < 4; reg++) {
                int gm = m0 + wm * 64 + fm * 16 + q4 * 4 + reg;
#pragma unroll
                for (int fn = 0; fn < 2; fn++) {
                    int gc = c0 + wn * 32 + fn * 16 + i15;
                    out[(size_t)gm * 512 + gc] = acc[fm][fn][reg] + bias[gc];
                }
            }
    } else {
        __syncthreads();                       // panel dead; reuse as scratch
        float2* rowred = (float2*)smem;        // [8 waves][64 rows]
        float2* colred = (float2*)(smem + 4096);  // [8 waves][32 cols]
        float2* lnfin  = (float2*)(smem + 6144);  // [2 hp][128 rows] (inv,mean)
        int t = m0 >> 13;
        int nbase = m0 & 1023;
        int rr = m0 & 8191, qg = rr >> 10, nblk = (rr >> 7) & 7;
        int hp = wn >> 1;
        int h = (c0 >> 6) + hp, hq = h * 8 + qg;
        int dwn = (wn & 1) * 32;
        float u_[2], cb_[2];
#pragma unroll
        for (int fn = 0; fn < 2; fn++) {
            int gc = c0 + wn * 32 + fn * 16 + i15;
            u_[fn] = ws[WS_U + gc]; cb_[fn] = ws[WS_CB + gc];
        }
        float csum[2] = {0, 0}, css[2] = {0, 0};
#pragma unroll
        for (int fm = 0; fm < 4; fm++) {
#pragma unroll
            for (int reg = 0; reg < 4; reg++) {
                int gm = m0 + wm * 64 + fm * 16 + q4 * 4 + reg;
                float2 st = *(const float2*)(ws + WS_LNST + (size_t)gm * 2);
                float mu = st.x, rs = st.y;
                float r1 = 0.f, r2 = 0.f;
#pragma unroll
                for (int fn = 0; fn < 2; fn++) {
                    float val = rs * acc[fm][fn][reg] - rs * mu * u_[fn] + cb_[fn];
                    acc[fm][fn][reg] = val;    // keep for final writes
                    r1 += val; r2 += val * val;
                    csum[fn] += val; css[fn] += val * val;
                }
                if (t < 2) {
#pragma unroll
                    for (int m = 1; m < 16; m <<= 1) {
                        r1 += __shfl_xor(r1, m, 64);
                        r2 += __shfl_xor(r2, m, 64);
                    }
                    if (i15 == fm * 4 + reg)
                        rowred[(size_t)wid * 64 + fm * 16 + q4 * 4 + reg] = (float2){r1, r2};
                }
            }
        }
        if (t < 2) {
#pragma unroll
            for (int fn = 0; fn < 2; fn++) {
                float s1 = csum[fn], s2 = css[fn];
                s1 += __shfl_xor(s1, 16, 64); s1 += __shfl_xor(s1, 32, 64);
                s2 += __shfl_xor(s2, 16, 64); s2 += __shfl_xor(s2, 32, 64);
                if (q4 == fn) colred[(size_t)wid * 32 + fn * 16 + i15] = (float2){s1, s2};
            }
        }
        __syncthreads();
        if (t < 2) {
            float* invn = ws + (t ? WS_INVNK : WS_INVNQ);
            float* mean = ws + (t ? WS_KMEAN : WS_QMEAN);
            if (tid < 256) {                   // 2 wm x 2 headpair x 64 rows
                int wmf = tid >> 7, p = (tid >> 6) & 1, r = tid & 63;
                float2 aa = rowred[(size_t)(wmf * 4 + 2 * p) * 64 + r];
                float2 bb = rowred[(size_t)(wmf * 4 + 2 * p + 1) * 64 + r];
                float s1 = aa.x + bb.x, s2 = aa.y + bb.y;
                float iv = rsqrtf(s2), mn = s1 * (1.f / 64.f);
                int n = nbase + wmf * 64 + r;
                int hhq = ((c0 >> 6) + p) * 8 + qg;
                invn[(size_t)hhq * 1024 + n] = iv;
                mean[(size_t)hhq * 1024 + n] = mn;
                lnfin[p * 128 + wmf * 64 + r] = (float2){iv, mn};
            } else if (tid < 384) {            // 2 headpair x 64 cols
                int tt = tid - 256;
                int p = tt >> 6, d = tt & 63;
                int wnn = 2 * p + (d >> 5), loc = d & 31;
                float2 aa = colred[(size_t)(0 * 4 + wnn) * 32 + loc];
                float2 bb = colred[(size_t)(1 * 4 + wnn) * 32 + loc];
                int hhq = ((c0 >> 6) + p) * 8 + qg;
                *(float2*)(ws + WS_COLP +
                           (size_t)(((t * 64 + hhq) * 8 + nblk) * 64 + d) * 2) =
                    (float2){aa.x + bb.x, aa.y + bb.y};
            }
        }
        __syncthreads();
        if (t == 0) {                          // FQ row-major [hq][n][64]
            u16* fout = (u16*)(ws + WS_FQ) + (size_t)hq * 65536;
#pragma unroll
            for (int fm = 0; fm < 4; fm++)
#pragma unroll
                for (int reg = 0; reg < 4; reg++) {
                    int n = nbase + wm * 64 + fm * 16 + q4 * 4 + reg;
#pragma unroll
                    for (int fn = 0; fn < 2; fn++)
                        fout[(size_t)n * 64 + dwn + fn * 16 + i15] =
                            f2bf(acc[fm][fn][reg]);
                }
        } else if (t == 1) {                   // FKTs/FKTc fragment layout
            u16* fs = (u16*)(ws + WS_FKTS) + (size_t)hq * 65536;
            u16* fc = (u16*)(ws + WS_FKTC) + (size_t)hq * 65536;
#pragma unroll
            for (int fn = 0; fn < 2; fn++) {
                int eoff = ((wn & 1) * 2 + fn) * 16384 + i15 * 32;
#pragma unroll
                for (int fm = 0; fm < 4; fm++) {
                    int n0l = wm * 64 + fm * 16 + q4 * 4;
                    int n0 = nbase + n0l;
                    int off = eoff + (n0 >> 5) * 512 + ((n0 >> 3) & 3) * 8 + (n0 & 7);
                    u16x4 vs, vc;
#pragma unroll
                    for (int reg = 0; reg < 4; reg++) {
                        float2 im = lnfin[hp * 128 + n0l + reg];
                        float val = acc[fm][fn][reg];
                        vs[reg] = f2bf(val * im.x);
                        vc[reg] = f2bf(val - im.y);
                    }
                    *(u16x4*)(fs + off) = vs;
                    *(u16x4*)(fc + off) = vc;
                }
            }
        } else {                               // FVT fragment layout
            u16* fv = (u16*)(ws + WS_FVT) + (size_t)hq * 65536;
#pragma unroll
            for (int fn = 0; fn < 2; fn++) {
                int doff = ((wn & 1) * 2 + fn) * 16384 + i15 * 32;
#pragma unroll
                for (int fm = 0; fm < 4; fm++) {
                    int n0 = nbase + wm * 64 + fm * 16 + q4 * 4;
                    int off = doff + (n0 >> 5) * 512 + ((n0 >> 3) & 3) * 8 + (n0 & 7);
                    u16x4 v4;
#pragma unroll
                    for (int reg = 0; reg < 4; reg++) v4[reg] = f2bf(acc[fm][fn][reg]);
                    *(u16x4*)(fv + off) = v4;
                }
            }
        }
    }
}

// ---------------- K3a: parallel COLP reduction -> GSUM[2][8][64][2] --------
__global__ __launch_bounds__(256) void k_gatered(float* __restrict__ ws) {
    int h = blockIdx.x, t = blockIdx.y;
    int tid = threadIdx.x;
    int c = tid & 127, rg = tid >> 7;
    const float* base = ws + WS_COLP + ((size_t)(t * 64 + h * 8) * 8) * 128;
    float s = 0.f;
#pragma unroll 8
    for (int r = rg * 32; r < rg * 32 + 32; r++) s += base[(size_t)r * 128 + c];
    __shared__ float red[2][128];
    red[rg][c] = s;
    __syncthreads();
    if (tid < 128)
        ws[WS_GSUM + ((size_t)t * 8 + h) * 128 + tid] = red[0][tid] + red[1][tid];
}

// ---------------- K3b: gate MLP + variance penalty ----------------
__global__ __launch_bounds__(256) void k_gate(
    const float* __restrict__ pw1, const float* __restrict__ pb1,
    const float* __restrict__ plg, const float* __restrict__ plb,
    const float* __restrict__ pw2, const float* __restrict__ pb2,
    float* __restrict__ ws) {
    __shared__ float w1[128][64];
    __shared__ float gs[2][8][128];
    int tid = threadIdx.x, wid = tid >> 6, lane = tid & 63;
    for (int r = wid; r < 128; r += 4) w1[r][lane] = pw1[r * 64 + lane];
    for (int i = tid; i < 2048; i += 256) ((float*)gs)[i] = ws[WS_GSUM + i];
    __syncthreads();
    if (wid != 0) return;
    float Sq = 0, SSq = 0, Sk = 0, SSk = 0;
#pragma unroll
    for (int h = 0; h < 8; h++) {
        Sq += gs[0][h][lane * 2];  SSq += gs[0][h][lane * 2 + 1];
        Sk += gs[1][h][lane * 2];  SSk += gs[1][h][lane * 2 + 1];
    }
    const float NR = 65536.f;
    float stdq = sqrtf((SSq - Sq * Sq / NR) / (NR - 1.f) + 1e-4f);
    float stdk = sqrtf((SSk - Sk * Sk / NR) / (NR - 1.f) + 1e-4f);
    float vpen = (wsum(fmaxf(1.f - stdq, 0.f)) + wsum(fmaxf(1.f - stdk, 0.f))) * (1.f / 64.f);
    float gammav = plg[lane], betav = plb[lane], w2v = pw2[lane];
    for (int h = 0; h < 8; h++) {
        float y = pb1[lane];
#pragma unroll 8
        for (int i = 0; i < 64; i++) {
            y = fmaf(gs[0][h][i * 2] * (1.f / 8192.f), w1[i][lane], y);
            y = fmaf(gs[1][h][i * 2] * (1.f / 8192.f), w1[64 + i][lane], y);
        }
        float mu = wsum(y) * (1.f / 64.f);
        float dv = y - mu;
        float var = wsum(dv * dv) * (1.f / 64.f);
        float z = dv * rsqrtf(var + 1e-5f) * gammav + betav;
        float r = fmaxf(z, 0.f);
        float sdot = wsum(r * w2v);
        if (lane == 0) {
            float wv = 1.f / (1.f + expf(-(sdot + pb2[0])));
            ws[WS_WGATE + h] = wv / (1.f + vpen);
        }
    }
}

// ------- K4 (MFMA): M = FKTs@FVT^T-ish, C = FKTc@... per hq, K=1024 --------
// 4 waves split output 2x2 (e-half x d-half); barrier-free K loop; epilogue
// does the f32->bf16 transpose write of M^T/C^T + colC (old mcred folded in).
__global__ __launch_bounds__(256) void k_mc(float* __restrict__ ws) {
    int hq = blockIdx.x;
    int tid = threadIdx.x, wid = tid >> 6, lane = tid & 63;
    int i15 = lane & 15, q4 = lane >> 4;
    int we = wid >> 1, wd = wid & 1;
    const u16* fs = (const u16*)(ws + WS_FKTS) + (size_t)hq * 65536;
    const u16* fc = (const u16*)(ws + WS_FKTC) + (size_t)hq * 65536;
    const u16* fv = (const u16*)(ws + WS_FVT) + (size_t)hq * 65536;
    floatx4 aM[2][2], aC[2][2];
#pragma unroll
    for (int f = 0; f < 2; f++)
#pragma unroll
        for (int g = 0; g < 2; g++) {
            aM[f][g] = (floatx4){0.f, 0.f, 0.f, 0.f};
            aC[f][g] = (floatx4){0.f, 0.f, 0.f, 0.f};
        }
#pragma unroll 8
    for (int ks = 0; ks < 32; ks++) {
        short8 as_[2], ac_[2], b_[2];
#pragma unroll
        for (int f = 0; f < 2; f++) {
            int off = (we * 2 + f) * 16384 + ks * 512 + i15 * 32 + q4 * 8;
            as_[f] = *(const short8*)(fs + off);
            ac_[f] = *(const short8*)(fc + off);
        }
#pragma unroll
        for (int g = 0; g < 2; g++)
            b_[g] = *(const short8*)(fv + (wd * 2 + g) * 16384 + ks * 512 +
                                     i15 * 32 + q4 * 8);
#pragma unroll
        for (int f = 0; f < 2; f++)
#pragma unroll
            for (int g = 0; g < 2; g++) {
                aM[f][g] = __builtin_amdgcn_mfma_f32_16x16x32_bf16(
                    as_[f], b_[g], aM[f][g], 0, 0, 0);
                aC[f][g] = __builtin_amdgcn_mfma_f32_16x16x32_bf16(
                    ac_[f], b_[g], aC[f][g], 0, 0, 0);
            }
    }
    __shared__ float tile[2][64][65];
    __shared__ float cred[4][64];
#pragma unroll
    for (int f = 0; f < 2; f++)
#pragma unroll
        for (int g = 0; g < 2; g++)
#pragma unroll
            for (int reg = 0; reg < 4; reg++) {
                int e = we * 32 + f * 16 + q4 * 4 + reg;
                int d = wd * 32 + g * 16 + i15;
                tile[0][e][d] = aM[f][g][reg];
                tile[1][e][d] = aC[f][g][reg];
            }
    __syncthreads();
    int d = tid & 63, ec = tid >> 6;
    float cp = 0.f;
#pragma unroll
    for (int i = 0; i < 16; i++) cp += tile[1][ec * 16 + i][d];
    cred[ec][d] = cp;
#pragma unroll
    for (int mat = 0; mat < 2; mat++) {
        u16x8 p0, p1;
#pragma unroll
        for (int i = 0; i < 8; i++) {
            p0[i] = f2bf(tile[mat][ec * 16 + i][d]);
            p1[i] = f2bf(tile[mat][ec * 16 + 8 + i][d]);
        }
        u16* dst = (u16*)(ws + (mat ? WS_CTB : WS_MTB)) + (size_t)hq * 4096 + d * 64 + ec * 16;
        *(u16x8*)dst = p0;
        *(u16x8*)(dst + 8) = p1;
    }
    __syncthreads();
    if (tid < 64)
        ws[WS_COLC + (size_t)hq * 64 + tid] =
            cred[0][tid] + cred[1][tid] + cred[2][tid] + cred[3][tid];
}

// ---- K5 (MFMA, flipped): OUT^T[d][n] = c1*inv[n]*(M^T@fq^T) + c2*(...) ----
// A-frags = swizzled M^T/C^T from LDS; B-frags = FQ[n][e] direct (coalesced).
__global__ __launch_bounds__(256) void k_apply(float* __restrict__ ws) {
    int nt = blockIdx.x, hq = blockIdx.y;
    int h = hq >> 3, qg = hq & 7;
    __shared__ u16 mt[2][4096];                // swizzled M^T, C^T
    __shared__ float invqm[256][2];
    __shared__ u16 outs[256][66];
    int tid = threadIdx.x, wid = tid >> 6, lane = tid & 63;
    int i15 = lane & 15, q4 = lane >> 4;
#pragma unroll
    for (int mat = 0; mat < 2; mat++) {
        const u16* src = (const u16*)(ws + (mat ? WS_CTB : WS_MTB)) + (size_t)hq * 4096;
#pragma unroll
        for (int it = 0; it < 2; it++) {
            int i = tid + it * 256;
            int d = i >> 3, c8 = i & 7;
            u16x8 v = *(const u16x8*)(src + i * 8);
            int byte = d * 128 + ((c8 * 16) ^ ((d & 7) << 4));
            *(u16x8*)((char*)&mt[mat][0] + byte) = v;
        }
    }
    int R0 = nt * 256;
    invqm[tid][0] = ws[WS_INVNQ + (size_t)hq * 1024 + R0 + tid];
    invqm[tid][1] = ws[WS_QMEAN + (size_t)hq * 1024 + R0 + tid];
    float wv = ws[WS_WGATE + h];
    float c1 = 1.f - wv, c2 = wv * (1.f / 64.f);
    float4 ccv[4];
#pragma unroll
    for (int fm = 0; fm < 4; fm++)
        ccv[fm] = *(const float4*)(ws + WS_COLC + (size_t)hq * 64 + fm * 16 + q4 * 4);
    __syncthreads();
    const u16* fq = (const u16*)(ws + WS_FQ) + (size_t)hq * 65536;
    floatx4 aM[4][4], aC[4][4];
#pragma unroll
    for (int i = 0; i < 4; i++)
#pragma unroll
        for (int j = 0; j < 4; j++) {
            aM[i][j] = (floatx4){0.f, 0.f, 0.f, 0.f};
            aC[i][j] = (floatx4){0.f, 0.f, 0.f, 0.f};
        }
#pragma unroll
    for (int ks = 0; ks < 2; ks++) {
        short8 am_[4], ac_[4], bq[4];
#pragma unroll
        for (int f = 0; f < 4; f++) {
            int row = f * 16 + i15;
            int byte = row * 128 + ((q4 * 16 + ks * 64) ^ ((row & 7) << 4));
            am_[f] = *(const short8*)((char*)&mt[0][0] + byte);
            ac_[f] = *(const short8*)((char*)&mt[1][0] + byte);
        }
#pragma unroll
        for (int fn = 0; fn < 4; fn++) {
            int n = R0 + wid * 64 + fn * 16 + i15;
            bq[fn] = *(const short8*)(fq + (size_t)n * 64 + ks * 32 + q4 * 8);
        }
#pragma unroll
        for (int fm = 0; fm < 4; fm++)
#pragma unroll
            for (int fn = 0; fn < 4; fn++) {
                aM[fm][fn] = __builtin_amdgcn_mfma_f32_16x16x32_bf16(
                    am_[fm], bq[fn], aM[fm][fn], 0, 0, 0);
                aC[fm][fn] = __builtin_amdgcn_mfma_f32_16x16x32_bf16(
                    ac_[fm], bq[fn], aC[fm][fn], 0, 0, 0);
            }
    }
#pragma unroll
    for (int fn = 0; fn < 4; fn++) {
        int nloc = wid * 64 + fn * 16 + i15;
        float iv = invqm[nloc][0], qm = invqm[nloc][1];
#pragma unroll
        for (int fm = 0; fm < 4; fm++)
#pragma unroll
            for (int reg = 0; reg < 4; reg++) {
                float val = c1 * iv * aM[fm][fn][reg] +
                            c2 * (aC[fm][fn][reg] - qm * ccv[fm][reg]);
                outs[nloc][fm * 16 + q4 * 4 + reg] = f2bf(val);
            }
    }
    __syncthreads();
    u16* oat = (u16*)(ws + WS_OATT);
#pragma unroll
    for (int it = 0; it < 8; it++) {
        int c = tid + it * 256;
        int row = c >> 3, c8 = (c & 7) * 8;
        int gr = qg * 1024 + R0 + row;
        size_t off = (size_t)(gr >> 4) * 8192 + (size_t)(h * 2 + (c8 >> 5)) * 512 +
                     (row & 15) * 32 + ((c8 >> 3) & 3) * 8;
        *(u16x8*)(oat + off) = *(const u16x8*)&outs[row][c8];
    }
}

// ---------------- host launch ----------------
extern "C" void kernel_launch(void* const* d_in, const int* in_sizes, int n_in,
                              void* d_out, int out_size, void* d_ws, size_t ws_size,
                              hipStream_t stream) {
    (void)in_sizes; (void)n_in; (void)out_size; (void)ws_size;
    const float* q = (const float*)d_in[0];
    const float* k = (const float*)d_in[1];
    const float* v = (const float*)d_in[2];
    const float* ln_g = (const float*)d_in[3];
    const float* ln_b = (const float*)d_in[4];
    const float* w_in = (const float*)d_in[5];
    const float* p_w1 = (const float*)d_in[6];
    const float* p_b1 = (const float*)d_in[7];
    const float* p_ln_g = (const float*)d_in[8];
    const float* p_ln_b = (const float*)d_in[9];
    const float* p_w2 = (const float*)d_in[10];
    const float* p_b2 = (const float*)d_in[11];
    const float* w_out = (const float*)d_in[12];
    const float* b_out = (const float*)d_in[13];
    float* ws = (float*)d_ws;
    float* out = (float*)d_out;

    k_lnstats<<<6144, 256, 0, stream>>>(q, k, v, ws);
    k_prep_t<1><<<dim3(8, 8), 256, 0, stream>>>(w_in, ln_g, (u16*)(ws + WS_WPT), ws + WS_WTF32);
    k_prep_t<0><<<dim3(8, 8), 256, 0, stream>>>(w_out, nullptr, (u16*)(ws + WS_WOT), nullptr);
    k_prep_u<<<128, 256, 0, stream>>>(ln_g, ln_b, ws);
    k_gemm<0, 96><<<dim3(4, 192), 512, 0, stream>>>((const u16*)(ws + WS_XBF),
                                                    (const u16*)(ws + WS_WPT), ws, nullptr, nullptr);
    k_gatered<<<dim3(8, 2), 256, 0, stream>>>(ws);
    k_gate<<<1, 256, 0, stream>>>(p_w1, p_b1, p_ln_g, p_ln_b, p_w2, p_b2, ws);
    k_mc<<<64, 256, 0, stream>>>(ws);
    k_apply<<<dim3(4, 64), 256, 0, stream>>>(ws);
    k_gemm<1, 32><<<dim3(4, 64), 512, 0, stream>>>((const u16*)(ws + WS_OATT),
                                                   (const u16*)(ws + WS_WOT), ws, out, b_out);
}

// Round 8
// 141.895 us; speedup vs baseline: 1.0318x; 1.0318x over previous
//
#include <hip/hip_runtime.h>
#include <cstdint>

// ---------------- problem constants ----------------
// QG=8, N=1024, DIM=512, H=8, D=64; rows/tensor=8192; HQ=64
// A fragment layout ([rowblk16][S=k>>5][i15][q4][8] u16):
//   off = rowblk*8192 + S*512 + (row&15)*32 + ((k>>3)&3)*8

typedef unsigned short u16;
typedef unsigned int u32;
typedef __attribute__((ext_vector_type(8))) unsigned short u16x8;
typedef __attribute__((ext_vector_type(4))) unsigned short u16x4;
typedef __attribute__((ext_vector_type(8))) short short8;
typedef __attribute__((ext_vector_type(4))) float floatx4;

// ---------------- workspace layout (float offsets) ----------------
#define WS_XBF     0LL          // bf16 frag [1536 rowblk][8192]  (q,k,v stacked)
#define WS_MCP     0LL          // f32 [2][8][64][4096]  (aliases XBF, used after)
#define WS_OATT    4194304LL    // bf16 frag [512 rowblk][8192] (aliases XBF tail)
#define WS_WPT     6291456LL    // bf16 W'T [512][512]
#define WS_WOT     6422528LL    // bf16 w_outT [512][512]
#define WS_U       6553600LL    // f32 [512]  g@W_in
#define WS_CB      6554112LL    // f32 [512]  b@W_in
#define WS_LNST    6554624LL    // f32 [24576][2] (mu, rsigma)
#define WS_FQ      6603776LL    // bf16 [64 hq][1024 n][64 d] row-major
#define WS_FK      8700928LL
#define WS_FV      10798080LL
#define WS_INVNQ   12895232LL   // f32 [64][1024]
#define WS_INVNK   12960768LL
#define WS_QMEAN   13026304LL
#define WS_KMEAN   13091840LL
#define WS_COLP    13157376LL   // f32 [2][64][8][64][2] (sum, sumsq)
#define WS_WGATE   13288448LL   // f32 [8] (+pad)
#define WS_WTF32   13288512LL   // f32 WT [512][512] (prep-phase only)
#define WS_GSUM    13288512LL   // f32 [2][8][64][2] (gatered->gate only)
#define WS_MTB     13288512LL   // bf16 M^T [64 hq][64 d][64 e] (mcred->apply)
#define WS_CTB     13419584LL   // bf16 C^T
#define WS_COLC    13550656LL   // f32 [64][64] colsum of C
// end = 13554752 floats = 54.2 MB

__device__ __forceinline__ float wsum(float v) {
#pragma unroll
    for (int m = 32; m; m >>= 1) v += __shfl_xor(v, m, 64);
    return v;
}
__device__ __forceinline__ float rdlane(float v, int l) {
    return __int_as_float(__builtin_amdgcn_readlane(__float_as_int(v), l));
}
__device__ __forceinline__ u16 f2bf(float f) {
    u32 u = __float_as_uint(f);
    u32 r = u + 0x7fffu + ((u >> 16) & 1u);
    return (u16)(r >> 16);
}
__device__ __forceinline__ float bf2f(u16 u) {
    return __uint_as_float(((u32)u) << 16);
}

// ---------------- K0: LN row stats over DIM=512 + bf16 frag-layout copy ----
__global__ __launch_bounds__(256) void k_lnstats(
    const float* __restrict__ q, const float* __restrict__ k,
    const float* __restrict__ v, float* __restrict__ ws) {
    int wid = threadIdx.x >> 6, lane = threadIdx.x & 63;
    int row = blockIdx.x * 4 + wid;            // 0..24575
    int t = row >> 13, r = row & 8191;
    const float* src = (t == 0) ? q : ((t == 1) ? k : v);
    const float4* p = (const float4*)(src + (size_t)r * 512) + lane * 2;
    float4 a = p[0], b = p[1];
    u16x8 o;
    o[0] = f2bf(a.x); o[1] = f2bf(a.y); o[2] = f2bf(a.z); o[3] = f2bf(a.w);
    o[4] = f2bf(b.x); o[5] = f2bf(b.y); o[6] = f2bf(b.z); o[7] = f2bf(b.w);
    // frag layout: k = lane*8 -> S = lane>>2, q4 = lane&3
    *(u16x8*)((u16*)(ws + WS_XBF) + (size_t)(row >> 4) * 8192 +
              (lane >> 2) * 512 + (row & 15) * 32 + (lane & 3) * 8) = o;
    float s = a.x + a.y + a.z + a.w + b.x + b.y + b.z + b.w;
    float ss = a.x * a.x + a.y * a.y + a.z * a.z + a.w * a.w +
               b.x * b.x + b.y * b.y + b.z * b.z + b.w * b.w;
    s = wsum(s); ss = wsum(ss);
    if (lane == 0) {
        float mu = s * (1.f / 512.f);
        float var = ss * (1.f / 512.f) - mu * mu;
        ws[WS_LNST + (size_t)row * 2] = mu;
        ws[WS_LNST + (size_t)row * 2 + 1] = rsqrtf(var + 1e-5f);
    }
}

// ---------------- prep: transposed (scaled) bf16 weights ----------------
template <int SCALE>
__global__ __launch_bounds__(256) void k_prep_t(
    const float* __restrict__ W, const float* __restrict__ g,
    u16* __restrict__ Tb, float* __restrict__ Tf) {
    __shared__ float tile[64][65];
    int k0 = blockIdx.x * 64, j0 = blockIdx.y * 64;
    int tid = threadIdx.x;
    int c = (tid & 15) * 4, r0 = tid >> 4;
#pragma unroll
    for (int p = 0; p < 4; p++) {
        int r = r0 + p * 16;
        *(float4*)&tile[r][c] = *(const float4*)(W + (size_t)(k0 + r) * 512 + j0 + c);
    }
    __syncthreads();
    int kc = (tid & 15) * 4, jr0 = tid >> 4;
#pragma unroll
    for (int p = 0; p < 4; p++) {
        int jr = jr0 + p * 16;
        float v0 = tile[kc + 0][jr], v1 = tile[kc + 1][jr];
        float v2 = tile[kc + 2][jr], v3 = tile[kc + 3][jr];
        if (SCALE) {
            *(float4*)(Tf + (size_t)(j0 + jr) * 512 + k0 + kc) = (float4){v0, v1, v2, v3};
            v0 *= g[k0 + kc + 0]; v1 *= g[k0 + kc + 1];
            v2 *= g[k0 + kc + 2]; v3 *= g[k0 + kc + 3];
        }
        u16x4 ob = {f2bf(v0), f2bf(v1), f2bf(v2), f2bf(v3)};
        *(u16x4*)(Tb + (size_t)(j0 + jr) * 512 + k0 + kc) = ob;
    }
}

// ---------------- prep2: u = g@W, cb = b@W (from WT f32) ----------------
__global__ __launch_bounds__(256) void k_prep_u(
    const float* __restrict__ g, const float* __restrict__ b, float* __restrict__ ws) {
    int wid = threadIdx.x >> 6, lane = threadIdx.x & 63;
    int j = blockIdx.x * 4 + wid;              // 0..511
    const float* Tf = ws + WS_WTF32 + (size_t)j * 512;
    float su = 0.f, sc = 0.f;
#pragma unroll
    for (int m = 0; m < 8; m++) {
        int k = lane * 8 + m;
        float w = Tf[k];
        su += g[k] * w; sc += b[k] * w;
    }
    su = wsum(su); sc = wsum(sc);
    if (lane == 0) { ws[WS_U + j] = su; ws[WS_CB + j] = sc; }
}

// ---------------- bf16 MFMA GEMM, 128x128 tile, BK=32, 8 waves -------------
// Hybrid: A per-wave direct from frag-layout global (2-deep reg pipeline),
// B staged in LDS 3-buf (rotation swizzle, proven 0-conflict), counted vmcnt.
// Wave grid 2(M)x4(N); wave tile 64x32 -> 4x2 fragments.
// MODE 0 (proj): epilogue f = rs*acc - rs*mu*u + cb, bf16 scatter + fused stats
// MODE 1 (out): +bias, f32 row-major.  CPX = gridblocks/8 (XCD swizzle).
template <int MODE, int CPX>
__global__ __launch_bounds__(512, 4) void k_gemm(
    const u16* __restrict__ A, const u16* __restrict__ B,
    float* __restrict__ ws, float* __restrict__ out, const float* __restrict__ bias) {
    __shared__ char smem[24576];               // 3 bufs x B 8K
    int tid = threadIdx.x;
    int wid = tid >> 6, lane = tid & 63;
    int i15 = lane & 15, q4 = lane >> 4;
    int wm = wid >> 2, wn = wid & 3;
    int flat = blockIdx.x + (blockIdx.y << 2);
    int swz = (flat & 7) * CPX + (flat >> 3);
    int c0 = (swz & 3) * 128, m0 = (swz >> 2) * 128;

    floatx4 acc[4][2];
#pragma unroll
    for (int i = 0; i < 4; i++)
#pragma unroll
        for (int j = 0; j < 2; j++) acc[i][j] = (floatx4){0.f, 0.f, 0.f, 0.f};

    const u16* gB = B + (size_t)c0 * 512;
    int arb = (m0 >> 4) + wm * 4;              // A rowblk base for this wave

    // stage 8KB B tile (128 cols x 32 k), rotation swizzle, 1 glds/wave
    auto stageB = [&](int ks, int buf) {
        int o = wid * 1024 + lane * 16;        // byte off in 8KB region
        int srow = o >> 6, s = (o >> 4) & 3;
        int cch = (s - (srow >> 1)) & 3;       // inverse rotation
        const u16* gb = gB + (size_t)srow * 512 + ks * 32 + cch * 8;
        char* lb = smem + buf * 8192 + wid * 1024;
        __builtin_amdgcn_global_load_lds(
            (const __attribute__((address_space(1))) void*)gb,
            (__attribute__((address_space(3))) void*)lb, 16, 0, 0);
    };
    auto loadA = [&](int ks, short8* dst) {
#pragma unroll
        for (int f = 0; f < 4; f++)
            dst[f] = *(const short8*)(A + (size_t)(arb + f) * 8192 + ks * 512 +
                                      i15 * 32 + q4 * 8);
    };

    short8 areg[2][4];
    stageB(0, 0);
    stageB(1, 1);
    loadA(0, areg[0]);
    __builtin_amdgcn_sched_barrier(0);
#pragma unroll
    for (int ks = 0; ks < 16; ks++) {
        __builtin_amdgcn_sched_barrier(0);
        if (ks < 15) asm volatile("s_waitcnt vmcnt(5)" ::: "memory");
        else         asm volatile("s_waitcnt vmcnt(4)" ::: "memory");
        __builtin_amdgcn_s_barrier();
        __builtin_amdgcn_sched_barrier(0);
        if (ks + 2 < 16) stageB(ks + 2, (ks + 2) % 3);
        if (ks + 1 < 16) loadA(ks + 1, areg[(ks + 1) & 1]);
        __builtin_amdgcn_sched_barrier(0);     // pin prefetch below the wait
        int buf = ks % 3;
        short8 b[2];
#pragma unroll
        for (int f = 0; f < 2; f++) {
            int rb = wn * 32 + f * 16 + i15;
            int sb = (q4 + (rb >> 1)) & 3;     // rotation swizzle
            b[f] = *(const short8*)(smem + buf * 8192 + rb * 64 + sb * 16);
        }
#pragma unroll
        for (int fm = 0; fm < 4; fm++)
#pragma unroll
            for (int fn = 0; fn < 2; fn++)
                acc[fm][fn] = __builtin_amdgcn_mfma_f32_16x16x32_bf16(
                    areg[ks & 1][fm], b[fn], acc[fm][fn], 0, 0, 0);
    }

    if constexpr (MODE == 1) {
#pragma unroll
        for (int fm = 0; fm < 4; fm++)
#pragma unroll
            for (int reg = 0; reg < 4; reg++) {
                int gm = m0 + wm * 64 + fm * 16 + q4 * 4 + reg;
#pragma unroll
                for (int fn = 0; fn < 2; fn++) {
                    int gc = c0 + wn * 32 + fn * 16 + i15;
                    out[(size_t)gm * 512 + gc] = acc[fm][fn][reg] + bias[gc];
                }
            }
    } else {
        __syncthreads();                       // B bufs dead; reuse as scratch
        float2* rowred = (float2*)smem;        // [8 waves][64 rows]
        float2* colred = (float2*)(smem + 4096);  // [8 waves][32 cols]
        int t = m0 >> 13;
        int rr = m0 & 8191, qg = rr >> 10, nblk = (rr >> 7) & 7;
        int h = (c0 >> 6) + (wn >> 1), hq = h * 8 + qg;
        int dwn = (wn & 1) * 32;
        u16* fout = (u16*)(ws + (t == 0 ? WS_FQ : t == 1 ? WS_FK : WS_FV));
        float u_[2], cb_[2];
#pragma unroll
        for (int fn = 0; fn < 2; fn++) {
            int gc = c0 + wn * 32 + fn * 16 + i15;
            u_[fn] = ws[WS_U + gc]; cb_[fn] = ws[WS_CB + gc];
        }
        float csum[2] = {0, 0}, css[2] = {0, 0};
#pragma unroll
        for (int fm = 0; fm < 4; fm++) {
#pragma unroll
            for (int reg = 0; reg < 4; reg++) {
                int gm = m0 + wm * 64 + fm * 16 + q4 * 4 + reg;
                float2 st = *(const float2*)(ws + WS_LNST + (size_t)gm * 2);
                float mu = st.x, rs = st.y;
                int n = gm & 1023;
                float r1 = 0.f, r2 = 0.f;
#pragma unroll
                for (int fn = 0; fn < 2; fn++) {
                    float val = rs * acc[fm][fn][reg] - rs * mu * u_[fn] + cb_[fn];
                    fout[(size_t)hq * 65536 + n * 64 + dwn + fn * 16 + i15] = f2bf(val);
                    r1 += val; r2 += val * val;
                    csum[fn] += val; css[fn] += val * val;
                }
                if (t < 2) {
#pragma unroll
                    for (int m = 1; m < 16; m <<= 1) {
                        r1 += __shfl_xor(r1, m, 64);
                        r2 += __shfl_xor(r2, m, 64);
                    }
                    if (i15 == fm * 4 + reg)
                        rowred[(size_t)wid * 64 + fm * 16 + q4 * 4 + reg] = (float2){r1, r2};
                }
            }
        }
        if (t < 2) {
#pragma unroll
            for (int fn = 0; fn < 2; fn++) {
                float s1 = csum[fn], s2 = css[fn];
                s1 += __shfl_xor(s1, 16, 64); s1 += __shfl_xor(s1, 32, 64);
                s2 += __shfl_xor(s2, 16, 64); s2 += __shfl_xor(s2, 32, 64);
                if (q4 == fn) colred[(size_t)wid * 32 + fn * 16 + i15] = (float2){s1, s2};
            }
        }
        __syncthreads();
        if (t < 2) {
            float* invn = ws + (t ? WS_INVNK : WS_INVNQ);
            float* mean = ws + (t ? WS_KMEAN : WS_QMEAN);
            if (tid < 256) {                   // 2 wm x 2 headpair x 64 rows
                int wmf = tid >> 7, p = (tid >> 6) & 1, r = tid & 63;
                float2 aa = rowred[(size_t)(wmf * 4 + 2 * p) * 64 + r];
                float2 bb = rowred[(size_t)(wmf * 4 + 2 * p + 1) * 64 + r];
                float s1 = aa.x + bb.x, s2 = aa.y + bb.y;
                int n = (m0 & 1023) + wmf * 64 + r;
                int hhq = ((c0 >> 6) + p) * 8 + qg;
                invn[(size_t)hhq * 1024 + n] = rsqrtf(s2);
                mean[(size_t)hhq * 1024 + n] = s1 * (1.f / 64.f);
            } else if (tid < 384) {            // 2 headpair x 64 cols
                int tt = tid - 256;
                int p = tt >> 6, d = tt & 63;
                int wnn = 2 * p + (d >> 5), loc = d & 31;
                float2 aa = colred[(size_t)(0 * 4 + wnn) * 32 + loc];
                float2 bb = colred[(size_t)(1 * 4 + wnn) * 32 + loc];
                int hhq = ((c0 >> 6) + p) * 8 + qg;
                *(float2*)(ws + WS_COLP +
                           (size_t)(((t * 64 + hhq) * 8 + nblk) * 64 + d) * 2) =
                    (float2){aa.x + bb.x, aa.y + bb.y};
            }
        }
    }
}

// ---------------- K3a: parallel COLP reduction -> GSUM[2][8][64][2] --------
__global__ __launch_bounds__(256) void k_gatered(float* __restrict__ ws) {
    int h = blockIdx.x, t = blockIdx.y;
    int tid = threadIdx.x;
    int c = tid & 127, rg = tid >> 7;
    const float* base = ws + WS_COLP + ((size_t)(t * 64 + h * 8) * 8) * 128;
    float s = 0.f;
#pragma unroll 8
    for (int r = rg * 32; r < rg * 32 + 32; r++) s += base[(size_t)r * 128 + c];
    __shared__ float red[2][128];
    red[rg][c] = s;
    __syncthreads();
    if (tid < 128)
        ws[WS_GSUM + ((size_t)t * 8 + h) * 128 + tid] = red[0][tid] + red[1][tid];
}

// ---------------- K3b: gate MLP + variance penalty ----------------
__global__ __launch_bounds__(256) void k_gate(
    const float* __restrict__ pw1, const float* __restrict__ pb1,
    const float* __restrict__ plg, const float* __restrict__ plb,
    const float* __restrict__ pw2, const float* __restrict__ pb2,
    float* __restrict__ ws) {
    __shared__ float w1[128][64];
    __shared__ float gs[2][8][128];
    int tid = threadIdx.x, wid = tid >> 6, lane = tid & 63;
    for (int r = wid; r < 128; r += 4) w1[r][lane] = pw1[r * 64 + lane];
    for (int i = tid; i < 2048; i += 256) ((float*)gs)[i] = ws[WS_GSUM + i];
    __syncthreads();
    if (wid != 0) return;
    float Sq = 0, SSq = 0, Sk = 0, SSk = 0;
#pragma unroll
    for (int h = 0; h < 8; h++) {
        Sq += gs[0][h][lane * 2];  SSq += gs[0][h][lane * 2 + 1];
        Sk += gs[1][h][lane * 2];  SSk += gs[1][h][lane * 2 + 1];
    }
    const float NR = 65536.f;
    float stdq = sqrtf((SSq - Sq * Sq / NR) / (NR - 1.f) + 1e-4f);
    float stdk = sqrtf((SSk - Sk * Sk / NR) / (NR - 1.f) + 1e-4f);
    float vpen = (wsum(fmaxf(1.f - stdq, 0.f)) + wsum(fmaxf(1.f - stdk, 0.f))) * (1.f / 64.f);
    float gammav = plg[lane], betav = plb[lane], w2v = pw2[lane];
    for (int h = 0; h < 8; h++) {
        float y = pb1[lane];
#pragma unroll 8
        for (int i = 0; i < 64; i++) {
            y = fmaf(gs[0][h][i * 2] * (1.f / 8192.f), w1[i][lane], y);
            y = fmaf(gs[1][h][i * 2] * (1.f / 8192.f), w1[64 + i][lane], y);
        }
        float mu = wsum(y) * (1.f / 64.f);
        float dv = y - mu;
        float var = wsum(dv * dv) * (1.f / 64.f);
        float z = dv * rsqrtf(var + 1e-5f) * gammav + betav;
        float r = fmaxf(z, 0.f);
        float sdot = wsum(r * w2v);
        if (lane == 0) {
            float wv = 1.f / (1.f + expf(-(sdot + pb2[0])));
            ws[WS_WGATE + h] = wv / (1.f + vpen);
        }
    }
}

// ---------------- K4: build M,C (64x64 per hq), split-K over 8 parts -------
__global__ __launch_bounds__(256) void k_mc(float* __restrict__ ws) {
    int part = blockIdx.x, hq = blockIdx.y;
    const u16* fk = (const u16*)(ws + WS_FK) + (size_t)hq * 65536;
    const u16* fv = (const u16*)(ws + WS_FV) + (size_t)hq * 65536;
    const float* invk = ws + WS_INVNK + (size_t)hq * 1024;
    const float* kmg = ws + WS_KMEAN + (size_t)hq * 1024;
    __shared__ float fks[64][68], fkc[64][68], fvs[64][68];
    int tid = threadIdx.x;
    int e2 = (tid & 31) * 2, d0 = (tid >> 5) * 8;
    float am[2][8], ac[2][8];
#pragma unroll
    for (int r = 0; r < 2; r++)
#pragma unroll
        for (int j = 0; j < 8; j++) { am[r][j] = 0.f; ac[r][j] = 0.f; }

    for (int ch = 0; ch < 2; ch++) {
        int m0 = part * 128 + ch * 64;
        {
            int mr = tid >> 2, cq = (tid & 3) * 16;
            float inv = invk[m0 + mr], km = kmg[m0 + mr];
            const u16* fkr = fk + (size_t)(m0 + mr) * 64 + cq;
            const u16* fvr = fv + (size_t)(m0 + mr) * 64 + cq;
            u16x8 k0v = *(const u16x8*)fkr, k1v = *(const u16x8*)(fkr + 8);
            u16x8 v0v = *(const u16x8*)fvr, v1v = *(const u16x8*)(fvr + 8);
#pragma unroll
            for (int j = 0; j < 8; j++) {
                float kf = bf2f(k0v[j]);
                fks[mr][cq + j] = kf * inv; fkc[mr][cq + j] = kf - km;
                fvs[mr][cq + j] = bf2f(v0v[j]);
                kf = bf2f(k1v[j]);
                fks[mr][cq + 8 + j] = kf * inv; fkc[mr][cq + 8 + j] = kf - km;
                fvs[mr][cq + 8 + j] = bf2f(v1v[j]);
            }
        }
        __syncthreads();
#pragma unroll 4
        for (int mm = 0; mm < 64; mm++) {
            float2 as = *(float2*)&fks[mm][e2];
            float2 av = *(float2*)&fkc[mm][e2];
            float b[8];
            *(float4*)(b) = *(float4*)&fvs[mm][d0];
            *(float4*)(b + 4) = *(float4*)&fvs[mm][d0 + 4];
#pragma unroll
            for (int j = 0; j < 8; j++) {
                am[0][j] = fmaf(as.x, b[j], am[0][j]);
                am[1][j] = fmaf(as.y, b[j], am[1][j]);
                ac[0][j] = fmaf(av.x, b[j], ac[0][j]);
                ac[1][j] = fmaf(av.y, b[j], ac[1][j]);
            }
        }
        __syncthreads();
    }
    float* pm = ws + WS_MCP + ((size_t)(0 * 8 + part) * 64 + hq) * 4096;
    float* pc = ws + WS_MCP + ((size_t)(1 * 8 + part) * 64 + hq) * 4096;
#pragma unroll
    for (int r = 0; r < 2; r++) {
        *(float4*)(pm + (e2 + r) * 64 + d0) = *(float4*)&am[r][0];
        *(float4*)(pm + (e2 + r) * 64 + d0 + 4) = *(float4*)&am[r][4];
        *(float4*)(pc + (e2 + r) * 64 + d0) = *(float4*)&ac[r][0];
        *(float4*)(pc + (e2 + r) * 64 + d0 + 4) = *(float4*)&ac[r][4];
    }
}

// ------- K4b: reduce split-K partials -> bf16 M^T,C^T + colC(f32) ----------
__global__ __launch_bounds__(256) void k_mcred(float* __restrict__ ws) {
    int hq = blockIdx.x;
    int tid = threadIdx.x;
    __shared__ float tile[2][64][65];
    __shared__ float cred[4][64];
    int e = tid & 63, dc = tid >> 6;
#pragma unroll
    for (int mat = 0; mat < 2; mat++) {
#pragma unroll
        for (int dq = 0; dq < 4; dq++) {
            int d0 = dc * 16 + dq * 4;
            float4 s = {0.f, 0.f, 0.f, 0.f};
#pragma unroll
            for (int p = 0; p < 8; p++) {
                const float* src = ws + WS_MCP +
                    ((size_t)(mat * 8 + p) * 64 + hq) * 4096 + e * 64 + d0;
                float4 vv = *(const float4*)src;
                s.x += vv.x; s.y += vv.y; s.z += vv.z; s.w += vv.w;
            }
            tile[mat][e][d0 + 0] = s.x; tile[mat][e][d0 + 1] = s.y;
            tile[mat][e][d0 + 2] = s.z; tile[mat][e][d0 + 3] = s.w;
        }
    }
    __syncthreads();
    int d = tid & 63, ec = tid >> 6;
    float cp = 0.f;
#pragma unroll
    for (int i = 0; i < 16; i++) cp += tile[1][ec * 16 + i][d];
    cred[ec][d] = cp;
#pragma unroll
    for (int mat = 0; mat < 2; mat++) {
        u16x8 p0, p1;
#pragma unroll
        for (int i = 0; i < 8; i++) {
            p0[i] = f2bf(tile[mat][ec * 16 + i][d]);
            p1[i] = f2bf(tile[mat][ec * 16 + 8 + i][d]);
        }
        u16* dst = (u16*)(ws + (mat ? WS_CTB : WS_MTB)) + (size_t)hq * 4096 + d * 64 + ec * 16;
        *(u16x8*)dst = p0;
        *(u16x8*)(dst + 8) = p1;
    }
    __syncthreads();
    if (tid < 64)
        ws[WS_COLC + (size_t)hq * 64 + tid] =
            cred[0][tid] + cred[1][tid] + cred[2][tid] + cred[3][tid];
}

// ---- K5 (MFMA): out_attn = c1*inv*(fq@M) + c2*(fq@C - qm*colC), frag out --
__global__ __launch_bounds__(256) void k_apply(float* __restrict__ ws) {
    int nt = blockIdx.x, hq = blockIdx.y;
    int h = hq >> 3, qg = hq & 7;
    __shared__ u16 mt[2][4096];                // swizzled M^T, C^T (8KB each)
    __shared__ float invqm[256][2];
    __shared__ u16 outs[256][66];              // +2 pad
    int tid = threadIdx.x, wid = tid >> 6, lane = tid & 63;
    int i15 = lane & 15, q4 = lane >> 4;
#pragma unroll
    for (int mat = 0; mat < 2; mat++) {
        const u16* src = (const u16*)(ws + (mat ? WS_CTB : WS_MTB)) + (size_t)hq * 4096;
#pragma unroll
        for (int it = 0; it < 2; it++) {
            int i = tid + it * 256;            // 16B chunk id, 512 total
            int d = i >> 3, c8 = i & 7;
            u16x8 v = *(const u16x8*)(src + i * 8);
            int byte = d * 128 + ((c8 * 16) ^ ((d & 7) << 4));
            *(u16x8*)((char*)&mt[mat][0] + byte) = v;
        }
    }
    int R0 = nt * 256;
    invqm[tid][0] = ws[WS_INVNQ + (size_t)hq * 1024 + R0 + tid];
    invqm[tid][1] = ws[WS_QMEAN + (size_t)hq * 1024 + R0 + tid];
    float wv = ws[WS_WGATE + h];
    float c1 = 1.f - wv, c2 = wv * (1.f / 64.f);
    float colc[4];
#pragma unroll
    for (int fn = 0; fn < 4; fn++)
        colc[fn] = ws[WS_COLC + (size_t)hq * 64 + fn * 16 + i15];
    __syncthreads();
    const u16* fq = (const u16*)(ws + WS_FQ) + (size_t)hq * 65536 +
                    (size_t)(R0 + wid * 64) * 64;
    floatx4 aM[4][4], aC[4][4];
#pragma unroll
    for (int i = 0; i < 4; i++)
#pragma unroll
        for (int j = 0; j < 4; j++) {
            aM[i][j] = (floatx4){0.f, 0.f, 0.f, 0.f};
            aC[i][j] = (floatx4){0.f, 0.f, 0.f, 0.f};
        }
#pragma unroll
    for (int ks = 0; ks < 2; ks++) {
        short8 a[4], bM[4], bC[4];
#pragma unroll
        for (int f = 0; f < 4; f++)
            a[f] = *(const short8*)(fq + (size_t)(f * 16 + i15) * 64 + q4 * 8 + ks * 32);
#pragma unroll
        for (int f = 0; f < 4; f++) {
            int col = f * 16 + i15;
            int byte = col * 128 + ((q4 * 16 + ks * 64) ^ ((col & 7) << 4));
            bM[f] = *(const short8*)((char*)&mt[0][0] + byte);
            bC[f] = *(const short8*)((char*)&mt[1][0] + byte);
        }
#pragma unroll
        for (int fm = 0; fm < 4; fm++)
#pragma unroll
            for (int fn = 0; fn < 4; fn++) {
                aM[fm][fn] = __builtin_amdgcn_mfma_f32_16x16x32_bf16(
                    a[fm], bM[fn], aM[fm][fn], 0, 0, 0);
                aC[fm][fn] = __builtin_amdgcn_mfma_f32_16x16x32_bf16(
                    a[fm], bC[fn], aC[fm][fn], 0, 0, 0);
            }
    }
#pragma unroll
    for (int fm = 0; fm < 4; fm++)
#pragma unroll
        for (int reg = 0; reg < 4; reg++) {
            int rloc = wid * 64 + fm * 16 + q4 * 4 + reg;
            float iv = invqm[rloc][0], qmv = invqm[rloc][1];
#pragma unroll
            for (int fn = 0; fn < 4; fn++) {
                float val = c1 * iv * aM[fm][fn][reg] +
                            c2 * (aC[fm][fn][reg] - qmv * colc[fn]);
                outs[rloc][fn * 16 + i15] = f2bf(val);
            }
        }
    __syncthreads();
    u16* oat = (u16*)(ws + WS_OATT);
#pragma unroll
    for (int it = 0; it < 8; it++) {
        int c = tid + it * 256;                // 16B chunk id, 2048 total
        int row = c >> 3, c8 = (c & 7) * 8;
        int gr = qg * 1024 + R0 + row;
        size_t off = (size_t)(gr >> 4) * 8192 + (size_t)(h * 2 + (c8 >> 5)) * 512 +
                     (row & 15) * 32 + ((c8 >> 3) & 3) * 8;
        *(u16x8*)(oat + off) = *(const u16x8*)&outs[row][c8];
    }
}

// ---------------- host launch ----------------
extern "C" void kernel_launch(void* const* d_in, const int* in_sizes, int n_in,
                              void* d_out, int out_size, void* d_ws, size_t ws_size,
                              hipStream_t stream) {
    (void)in_sizes; (void)n_in; (void)out_size; (void)ws_size;
    const float* q = (const float*)d_in[0];
    const float* k = (const float*)d_in[1];
    const float* v = (const float*)d_in[2];
    const float* ln_g = (const float*)d_in[3];
    const float* ln_b = (const float*)d_in[4];
    const float* w_in = (const float*)d_in[5];
    const float* p_w1 = (const float*)d_in[6];
    const float* p_b1 = (const float*)d_in[7];
    const float* p_ln_g = (const float*)d_in[8];
    const float* p_ln_b = (const float*)d_in[9];
    const float* p_w2 = (const float*)d_in[10];
    const float* p_b2 = (const float*)d_in[11];
    const float* w_out = (const float*)d_in[12];
    const float* b_out = (const float*)d_in[13];
    float* ws = (float*)d_ws;
    float* out = (float*)d_out;

    k_lnstats<<<6144, 256, 0, stream>>>(q, k, v, ws);
    k_prep_t<1><<<dim3(8, 8), 256, 0, stream>>>(w_in, ln_g, (u16*)(ws + WS_WPT), ws + WS_WTF32);
    k_prep_t<0><<<dim3(8, 8), 256, 0, stream>>>(w_out, nullptr, (u16*)(ws + WS_WOT), nullptr);
    k_prep_u<<<128, 256, 0, stream>>>(ln_g, ln_b, ws);
    k_gemm<0, 96><<<dim3(4, 192), 512, 0, stream>>>((const u16*)(ws + WS_XBF),
                                                    (const u16*)(ws + WS_WPT), ws, nullptr, nullptr);
    k_gatered<<<dim3(8, 2), 256, 0, stream>>>(ws);
    k_gate<<<1, 256, 0, stream>>>(p_w1, p_b1, p_ln_g, p_ln_b, p_w2, p_b2, ws);
    k_mc<<<dim3(8, 64), 256, 0, stream>>>(ws);
    k_mcred<<<64, 256, 0, stream>>>(ws);
    k_apply<<<dim3(4, 64), 256, 0, stream>>>(ws);
    k_gemm<1, 32><<<dim3(4, 64), 512, 0, stream>>>((const u16*)(ws + WS_OATT),
                                                   (const u16*)(ws + WS_WOT), ws, out, b_out);
}

// Round 9
// 124.012 us; speedup vs baseline: 1.1806x; 1.1442x over previous
//
#include <hip/hip_runtime.h>
#include <cstdint>

// ---------------- problem constants ----------------
// QG=8, N=1024, DIM=512, H=8, D=64; rows/tensor=8192; HQ=64
// f layout: [hq][n][d] (bf16), idx = hq*65536 + n*64 + d

typedef unsigned short u16;
typedef unsigned int u32;
typedef __attribute__((ext_vector_type(8))) unsigned short u16x8;
typedef __attribute__((ext_vector_type(4))) unsigned short u16x4;
typedef __attribute__((ext_vector_type(8))) short short8;
typedef __attribute__((ext_vector_type(4))) float floatx4;

// ---------------- workspace layout (float offsets) ----------------
#define WS_XBF     0LL          // bf16 [24576][512]  (q,k,v stacked)
#define WS_MCP     0LL          // f32 [2][8][64][4096]  (aliases XBF, used after)
#define WS_OATT    4194304LL    // bf16 [8192][512]      (aliases XBF tail)
#define WS_WPT     6291456LL    // bf16 W'T [512][512]
#define WS_WOT     6422528LL    // bf16 w_outT [512][512]
#define WS_U       6553600LL    // f32 [512]  g@W_in
#define WS_CB      6554112LL    // f32 [512]  b@W_in
#define WS_LNST    6554624LL    // f32 [24576][2] (mu, rsigma)
#define WS_FQ      6603776LL    // bf16 [64][1024][64]
#define WS_FK      8700928LL
#define WS_FV      10798080LL
#define WS_INVNQ   12895232LL   // f32 [64][1024]
#define WS_INVNK   12960768LL
#define WS_QMEAN   13026304LL
#define WS_KMEAN   13091840LL
#define WS_COLP    13157376LL   // f32 [2][64][8][64][2] (sum, sumsq)
#define WS_WGATE   13288448LL   // f32 [8] (+pad)
#define WS_WTF32   13288512LL   // f32 WT [512][512] (prep-phase only)
#define WS_GSUM    13288512LL   // f32 [2][8][64][2] (gatered->gate only)
#define WS_MTB     13288512LL   // bf16 M^T [64 hq][64 d][64 e] (mcred->apply)
#define WS_CTB     13419584LL   // bf16 C^T
#define WS_COLC    13550656LL   // f32 [64][64] colsum of C
// end = 13554752 floats = 54.2 MB

__device__ __forceinline__ float wsum(float v) {
#pragma unroll
    for (int m = 32; m; m >>= 1) v += __shfl_xor(v, m, 64);
    return v;
}
__device__ __forceinline__ u16 f2bf(float f) {
    u32 u = __float_as_uint(f);
    u32 r = u + 0x7fffu + ((u >> 16) & 1u);
    return (u16)(r >> 16);
}
__device__ __forceinline__ float bf2f(u16 u) {
    return __uint_as_float(((u32)u) << 16);
}

// ---------------- K0: LN row stats over DIM=512 + bf16 copy ----------------
__global__ __launch_bounds__(256) void k_lnstats(
    const float* __restrict__ q, const float* __restrict__ k,
    const float* __restrict__ v, float* __restrict__ ws) {
    int wid = threadIdx.x >> 6, lane = threadIdx.x & 63;
    int row = blockIdx.x * 4 + wid;            // 0..24575
    int t = row >> 13, r = row & 8191;
    const float* src = (t == 0) ? q : ((t == 1) ? k : v);
    const float4* p = (const float4*)(src + (size_t)r * 512) + lane * 2;
    float4 a = p[0], b = p[1];
    u16x8 o;
    o[0] = f2bf(a.x); o[1] = f2bf(a.y); o[2] = f2bf(a.z); o[3] = f2bf(a.w);
    o[4] = f2bf(b.x); o[5] = f2bf(b.y); o[6] = f2bf(b.z); o[7] = f2bf(b.w);
    *(u16x8*)((u16*)(ws + WS_XBF) + (size_t)row * 512 + lane * 8) = o;
    float s = a.x + a.y + a.z + a.w + b.x + b.y + b.z + b.w;
    float ss = a.x * a.x + a.y * a.y + a.z * a.z + a.w * a.w +
               b.x * b.x + b.y * b.y + b.z * b.z + b.w * b.w;
    s = wsum(s); ss = wsum(ss);
    if (lane == 0) {
        float mu = s * (1.f / 512.f);
        float var = ss * (1.f / 512.f) - mu * mu;
        ws[WS_LNST + (size_t)row * 2] = mu;
        ws[WS_LNST + (size_t)row * 2 + 1] = rsqrtf(var + 1e-5f);
    }
}

// ---------------- prep: transposed (scaled) bf16 weights ----------------
template <int SCALE>
__global__ __launch_bounds__(256) void k_prep_t(
    const float* __restrict__ W, const float* __restrict__ g,
    u16* __restrict__ Tb, float* __restrict__ Tf) {
    __shared__ float tile[64][65];
    int k0 = blockIdx.x * 64, j0 = blockIdx.y * 64;
    int tid = threadIdx.x;
    int c = (tid & 15) * 4, r0 = tid >> 4;
#pragma unroll
    for (int p = 0; p < 4; p++) {
        int r = r0 + p * 16;
        *(float4*)&tile[r][c] = *(const float4*)(W + (size_t)(k0 + r) * 512 + j0 + c);
    }
    __syncthreads();
    int kc = (tid & 15) * 4, jr0 = tid >> 4;
#pragma unroll
    for (int p = 0; p < 4; p++) {
        int jr = jr0 + p * 16;
        float v0 = tile[kc + 0][jr], v1 = tile[kc + 1][jr];
        float v2 = tile[kc + 2][jr], v3 = tile[kc + 3][jr];
        if (SCALE) {
            *(float4*)(Tf + (size_t)(j0 + jr) * 512 + k0 + kc) = (float4){v0, v1, v2, v3};
            v0 *= g[k0 + kc + 0]; v1 *= g[k0 + kc + 1];
            v2 *= g[k0 + kc + 2]; v3 *= g[k0 + kc + 3];
        }
        u16x4 ob = {f2bf(v0), f2bf(v1), f2bf(v2), f2bf(v3)};
        *(u16x4*)(Tb + (size_t)(j0 + jr) * 512 + k0 + kc) = ob;
    }
}

// ---------------- prep2: u = g@W, cb = b@W (from WT f32) ----------------
__global__ __launch_bounds__(256) void k_prep_u(
    const float* __restrict__ g, const float* __restrict__ b, float* __restrict__ ws) {
    int wid = threadIdx.x >> 6, lane = threadIdx.x & 63;
    int j = blockIdx.x * 4 + wid;              // 0..511
    const float* Tf = ws + WS_WTF32 + (size_t)j * 512;
    float su = 0.f, sc = 0.f;
#pragma unroll
    for (int m = 0; m < 8; m++) {
        int k = lane * 8 + m;
        float w = Tf[k];
        su += g[k] * w; sc += b[k] * w;
    }
    su = wsum(su); sc = wsum(sc);
    if (lane == 0) { ws[WS_U + j] = su; ws[WS_CB + j] = sc; }
}

// ---------------- bf16 MFMA GEMM, 128x128 tile, BK=32, 8 waves -------------
// 4-stage LDS pipeline (depth-3 prefetch), counted vmcnt, stage issued
// post-barrier (overwrite-safe), XCD-bijective swizzle.
// Wave grid 2(M)x4(N); wave tile 64x32 -> 4x2 fragments.
// MODE 0 (proj): epilogue f = rs*acc - rs*mu*u + cb, bf16 scatter + fused stats
// MODE 1 (out): +bias, f32 row-major.  CPX = gridblocks/8 (per-XCD chunk).
template <int MODE, int CPX>
__global__ __launch_bounds__(512, 4) void k_gemm(
    const u16* __restrict__ A, const u16* __restrict__ B,
    float* __restrict__ ws, float* __restrict__ out, const float* __restrict__ bias) {
    __shared__ char smem[65536];               // 4 bufs x (A 8K + B 8K)
    int tid = threadIdx.x;
    int wid = tid >> 6, lane = tid & 63;
    int i15 = lane & 15, q4 = lane >> 4;
    int wm = wid >> 2, wn = wid & 3;
    int flat = blockIdx.x + (blockIdx.y << 2);
    int swz = (flat & 7) * CPX + (flat >> 3);
    int c0 = (swz & 3) * 128, m0 = (swz >> 2) * 128;

    floatx4 acc[4][2];
#pragma unroll
    for (int i = 0; i < 4; i++)
#pragma unroll
        for (int j = 0; j < 2; j++) acc[i][j] = (floatx4){0.f, 0.f, 0.f, 0.f};

    const u16* gA = A + (size_t)m0 * 512;
    const u16* gB = B + (size_t)c0 * 512;

    // each wave stages 1KB of A and 1KB of B per K-step (2 glds ops/wave)
    auto stage = [&](int ks, int buf) {
        int o = wid * 1024 + lane * 16;        // byte off in 8KB region
        int srow = o >> 6, s = (o >> 4) & 3;
        int cch = (s - (srow >> 1)) & 3;       // inverse rotation
        const u16* ga = gA + (size_t)srow * 512 + ks * 32 + cch * 8;
        const u16* gb = gB + (size_t)srow * 512 + ks * 32 + cch * 8;
        char* la = smem + buf * 16384 + wid * 1024;
        char* lb = smem + buf * 16384 + 8192 + wid * 1024;
        __builtin_amdgcn_global_load_lds(
            (const __attribute__((address_space(1))) void*)ga,
            (__attribute__((address_space(3))) void*)la, 16, 0, 0);
        __builtin_amdgcn_global_load_lds(
            (const __attribute__((address_space(1))) void*)gb,
            (__attribute__((address_space(3))) void*)lb, 16, 0, 0);
    };

    stage(0, 0);
    stage(1, 1);
    stage(2, 2);
    __builtin_amdgcn_sched_barrier(0);
#pragma unroll
    for (int ks = 0; ks < 16; ks++) {
        __builtin_amdgcn_sched_barrier(0);
        // in flight at this wait: stages ks+1, ks+2 (4 ops) -> vmcnt(4) proves
        // buf ks landed; tail drains 2 -> 0.
        if (ks <= 13)      asm volatile("s_waitcnt vmcnt(4)" ::: "memory");
        else if (ks == 14) asm volatile("s_waitcnt vmcnt(2)" ::: "memory");
        else               asm volatile("s_waitcnt vmcnt(0)" ::: "memory");
        __builtin_amdgcn_s_barrier();
        __builtin_amdgcn_sched_barrier(0);
        if (ks + 3 < 16) stage(ks + 3, (ks + 3) & 3);   // post-barrier: safe
        __builtin_amdgcn_sched_barrier(0);     // pin stage below the wait
        int buf = ks & 3;
        short8 a[4], b[2];
#pragma unroll
        for (int f = 0; f < 4; f++) {
            int ra = wm * 64 + f * 16 + i15;
            int sa = (q4 + (ra >> 1)) & 3;     // rotation swizzle
            a[f] = *(const short8*)(smem + buf * 16384 + ra * 64 + sa * 16);
        }
#pragma unroll
        for (int f = 0; f < 2; f++) {
            int rb = wn * 32 + f * 16 + i15;
            int sb = (q4 + (rb >> 1)) & 3;
            b[f] = *(const short8*)(smem + buf * 16384 + 8192 + rb * 64 + sb * 16);
        }
#pragma unroll
        for (int fm = 0; fm < 4; fm++)
#pragma unroll
            for (int fn = 0; fn < 2; fn++)
                acc[fm][fn] = __builtin_amdgcn_mfma_f32_16x16x32_bf16(
                    a[fm], b[fn], acc[fm][fn], 0, 0, 0);
    }

    if constexpr (MODE == 1) {
#pragma unroll
        for (int fm = 0; fm < 4; fm++)
#pragma unroll
            for (int reg = 0; reg < 4; reg++) {
                int gm = m0 + wm * 64 + fm * 16 + q4 * 4 + reg;
#pragma unroll
                for (int fn = 0; fn < 2; fn++) {
                    int gc = c0 + wn * 32 + fn * 16 + i15;
                    out[(size_t)gm * 512 + gc] = acc[fm][fn][reg] + bias[gc];
                }
            }
    } else {
        __syncthreads();                       // staging dead; reuse as scratch
        float2* rowred = (float2*)smem;        // [8 waves][64 rows]
        float2* colred = (float2*)(smem + 4096);  // [8 waves][32 cols]
        int t = m0 >> 13;
        int rr = m0 & 8191, qg = rr >> 10, nblk = (rr >> 7) & 7;
        int h = (c0 >> 6) + (wn >> 1), hq = h * 8 + qg;
        int dwn = (wn & 1) * 32;
        u16* fout = (u16*)(ws + (t == 0 ? WS_FQ : t == 1 ? WS_FK : WS_FV));
        float u_[2], cb_[2];
#pragma unroll
        for (int fn = 0; fn < 2; fn++) {
            int gc = c0 + wn * 32 + fn * 16 + i15;
            u_[fn] = ws[WS_U + gc]; cb_[fn] = ws[WS_CB + gc];
        }
        float csum[2] = {0, 0}, css[2] = {0, 0};
#pragma unroll
        for (int fm = 0; fm < 4; fm++) {
#pragma unroll
            for (int reg = 0; reg < 4; reg++) {
                int gm = m0 + wm * 64 + fm * 16 + q4 * 4 + reg;
                float2 st = *(const float2*)(ws + WS_LNST + (size_t)gm * 2);
                float mu = st.x, rs = st.y;
                int n = gm & 1023;
                float r1 = 0.f, r2 = 0.f;
#pragma unroll
                for (int fn = 0; fn < 2; fn++) {
                    float val = rs * acc[fm][fn][reg] - rs * mu * u_[fn] + cb_[fn];
                    fout[(size_t)hq * 65536 + n * 64 + dwn + fn * 16 + i15] = f2bf(val);
                    r1 += val; r2 += val * val;
                    csum[fn] += val; css[fn] += val * val;
                }
                if (t < 2) {
#pragma unroll
                    for (int m = 1; m < 16; m <<= 1) {
                        r1 += __shfl_xor(r1, m, 64);
                        r2 += __shfl_xor(r2, m, 64);
                    }
                    if (i15 == fm * 4 + reg)
                        rowred[(size_t)wid * 64 + fm * 16 + q4 * 4 + reg] = (float2){r1, r2};
                }
            }
        }
        if (t < 2) {
#pragma unroll
            for (int fn = 0; fn < 2; fn++) {
                float s1 = csum[fn], s2 = css[fn];
                s1 += __shfl_xor(s1, 16, 64); s1 += __shfl_xor(s1, 32, 64);
                s2 += __shfl_xor(s2, 16, 64); s2 += __shfl_xor(s2, 32, 64);
                if (q4 == fn) colred[(size_t)wid * 32 + fn * 16 + i15] = (float2){s1, s2};
            }
        }
        __syncthreads();
        if (t < 2) {
            float* invn = ws + (t ? WS_INVNK : WS_INVNQ);
            float* mean = ws + (t ? WS_KMEAN : WS_QMEAN);
            if (tid < 256) {                   // 2 wm x 2 headpair x 64 rows
                int wmf = tid >> 7, p = (tid >> 6) & 1, r = tid & 63;
                float2 aa = rowred[(size_t)(wmf * 4 + 2 * p) * 64 + r];
                float2 bb = rowred[(size_t)(wmf * 4 + 2 * p + 1) * 64 + r];
                float s1 = aa.x + bb.x, s2 = aa.y + bb.y;
                int n = (m0 & 1023) + wmf * 64 + r;
                int hhq = ((c0 >> 6) + p) * 8 + qg;
                invn[(size_t)hhq * 1024 + n] = rsqrtf(s2);
                mean[(size_t)hhq * 1024 + n] = s1 * (1.f / 64.f);
            } else if (tid < 384) {            // 2 headpair x 64 cols
                int tt = tid - 256;
                int p = tt >> 6, d = tt & 63;
                int wnn = 2 * p + (d >> 5), loc = d & 31;
                float2 aa = colred[(size_t)(0 * 4 + wnn) * 32 + loc];
                float2 bb = colred[(size_t)(1 * 4 + wnn) * 32 + loc];
                int hhq = ((c0 >> 6) + p) * 8 + qg;
                *(float2*)(ws + WS_COLP +
                           (size_t)(((t * 64 + hhq) * 8 + nblk) * 64 + d) * 2) =
                    (float2){aa.x + bb.x, aa.y + bb.y};
            }
        }
    }
}

// ---------------- K3a: parallel COLP reduction -> GSUM[2][8][64][2] --------
__global__ __launch_bounds__(256) void k_gatered(float* __restrict__ ws) {
    int h = blockIdx.x, t = blockIdx.y;
    int tid = threadIdx.x;
    int c = tid & 127, rg = tid >> 7;
    const float* base = ws + WS_COLP + ((size_t)(t * 64 + h * 8) * 8) * 128;
    float s = 0.f;
#pragma unroll 8
    for (int r = rg * 32; r < rg * 32 + 32; r++) s += base[(size_t)r * 128 + c];
    __shared__ float red[2][128];
    red[rg][c] = s;
    __syncthreads();
    if (tid < 128)
        ws[WS_GSUM + ((size_t)t * 8 + h) * 128 + tid] = red[0][tid] + red[1][tid];
}

// ---------------- K3b: gate MLP + variance penalty ----------------
__global__ __launch_bounds__(256) void k_gate(
    const float* __restrict__ pw1, const float* __restrict__ pb1,
    const float* __restrict__ plg, const float* __restrict__ plb,
    const float* __restrict__ pw2, const float* __restrict__ pb2,
    float* __restrict__ ws) {
    __shared__ float w1[128][64];
    __shared__ float gs[2][8][128];
    int tid = threadIdx.x, wid = tid >> 6, lane = tid & 63;
    for (int r = wid; r < 128; r += 4) w1[r][lane] = pw1[r * 64 + lane];
    for (int i = tid; i < 2048; i += 256) ((float*)gs)[i] = ws[WS_GSUM + i];
    __syncthreads();
    if (wid != 0) return;
    float Sq = 0, SSq = 0, Sk = 0, SSk = 0;
#pragma unroll
    for (int h = 0; h < 8; h++) {
        Sq += gs[0][h][lane * 2];  SSq += gs[0][h][lane * 2 + 1];
        Sk += gs[1][h][lane * 2];  SSk += gs[1][h][lane * 2 + 1];
    }
    const float NR = 65536.f;
    float stdq = sqrtf((SSq - Sq * Sq / NR) / (NR - 1.f) + 1e-4f);
    float stdk = sqrtf((SSk - Sk * Sk / NR) / (NR - 1.f) + 1e-4f);
    float vpen = (wsum(fmaxf(1.f - stdq, 0.f)) + wsum(fmaxf(1.f - stdk, 0.f))) * (1.f / 64.f);
    float gammav = plg[lane], betav = plb[lane], w2v = pw2[lane];
    for (int h = 0; h < 8; h++) {
        float y = pb1[lane];
#pragma unroll 8
        for (int i = 0; i < 64; i++) {
            y = fmaf(gs[0][h][i * 2] * (1.f / 8192.f), w1[i][lane], y);
            y = fmaf(gs[1][h][i * 2] * (1.f / 8192.f), w1[64 + i][lane], y);
        }
        float mu = wsum(y) * (1.f / 64.f);
        float dv = y - mu;
        float var = wsum(dv * dv) * (1.f / 64.f);
        float z = dv * rsqrtf(var + 1e-5f) * gammav + betav;
        float r = fmaxf(z, 0.f);
        float sdot = wsum(r * w2v);
        if (lane == 0) {
            float wv = 1.f / (1.f + expf(-(sdot + pb2[0])));
            ws[WS_WGATE + h] = wv / (1.f + vpen);
        }
    }
}

// ---------------- K4: build M,C (64x64 per hq), split-K over 8 parts -------
__global__ __launch_bounds__(256) void k_mc(float* __restrict__ ws) {
    int part = blockIdx.x, hq = blockIdx.y;
    const u16* fk = (const u16*)(ws + WS_FK) + (size_t)hq * 65536;
    const u16* fv = (const u16*)(ws + WS_FV) + (size_t)hq * 65536;
    const float* invk = ws + WS_INVNK + (size_t)hq * 1024;
    const float* kmg = ws + WS_KMEAN + (size_t)hq * 1024;
    __shared__ float fks[64][68], fkc[64][68], fvs[64][68];
    int tid = threadIdx.x;
    int e2 = (tid & 31) * 2, d0 = (tid >> 5) * 8;
    float am[2][8], ac[2][8];
#pragma unroll
    for (int r = 0; r < 2; r++)
#pragma unroll
        for (int j = 0; j < 8; j++) { am[r][j] = 0.f; ac[r][j] = 0.f; }

    for (int ch = 0; ch < 2; ch++) {
        int m0 = part * 128 + ch * 64;
        {
            int mr = tid >> 2, cq = (tid & 3) * 16;
            float inv = invk[m0 + mr], km = kmg[m0 + mr];
            const u16* fkr = fk + (size_t)(m0 + mr) * 64 + cq;
            const u16* fvr = fv + (size_t)(m0 + mr) * 64 + cq;
            u16x8 k0v = *(const u16x8*)fkr, k1v = *(const u16x8*)(fkr + 8);
            u16x8 v0v = *(const u16x8*)fvr, v1v = *(const u16x8*)(fvr + 8);
#pragma unroll
            for (int j = 0; j < 8; j++) {
                float kf = bf2f(k0v[j]);
                fks[mr][cq + j] = kf * inv; fkc[mr][cq + j] = kf - km;
                fvs[mr][cq + j] = bf2f(v0v[j]);
                kf = bf2f(k1v[j]);
                fks[mr][cq + 8 + j] = kf * inv; fkc[mr][cq + 8 + j] = kf - km;
                fvs[mr][cq + 8 + j] = bf2f(v1v[j]);
            }
        }
        __syncthreads();
#pragma unroll 4
        for (int mm = 0; mm < 64; mm++) {
            float2 as = *(float2*)&fks[mm][e2];
            float2 av = *(float2*)&fkc[mm][e2];
            float b[8];
            *(float4*)(b) = *(float4*)&fvs[mm][d0];
            *(float4*)(b + 4) = *(float4*)&fvs[mm][d0 + 4];
#pragma unroll
            for (int j = 0; j < 8; j++) {
                am[0][j] = fmaf(as.x, b[j], am[0][j]);
                am[1][j] = fmaf(as.y, b[j], am[1][j]);
                ac[0][j] = fmaf(av.x, b[j], ac[0][j]);
                ac[1][j] = fmaf(av.y, b[j], ac[1][j]);
            }
        }
        __syncthreads();
    }
    float* pm = ws + WS_MCP + ((size_t)(0 * 8 + part) * 64 + hq) * 4096;
    float* pc = ws + WS_MCP + ((size_t)(1 * 8 + part) * 64 + hq) * 4096;
#pragma unroll
    for (int r = 0; r < 2; r++) {
        *(float4*)(pm + (e2 + r) * 64 + d0) = *(float4*)&am[r][0];
        *(float4*)(pm + (e2 + r) * 64 + d0 + 4) = *(float4*)&am[r][4];
        *(float4*)(pc + (e2 + r) * 64 + d0) = *(float4*)&ac[r][0];
        *(float4*)(pc + (e2 + r) * 64 + d0 + 4) = *(float4*)&ac[r][4];
    }
}

// ------- K4b: reduce split-K partials -> bf16 M^T,C^T + colC(f32) ----------
__global__ __launch_bounds__(256) void k_mcred(float* __restrict__ ws) {
    int hq = blockIdx.x;
    int tid = threadIdx.x;
    __shared__ float tile[2][64][65];
    __shared__ float cred[4][64];
    int e = tid & 63, dc = tid >> 6;
#pragma unroll
    for (int mat = 0; mat < 2; mat++) {
#pragma unroll
        for (int dq = 0; dq < 4; dq++) {
            int d0 = dc * 16 + dq * 4;
            float4 s = {0.f, 0.f, 0.f, 0.f};
#pragma unroll
            for (int p = 0; p < 8; p++) {
                const float* src = ws + WS_MCP +
                    ((size_t)(mat * 8 + p) * 64 + hq) * 4096 + e * 64 + d0;
                float4 vv = *(const float4*)src;
                s.x += vv.x; s.y += vv.y; s.z += vv.z; s.w += vv.w;
            }
            tile[mat][e][d0 + 0] = s.x; tile[mat][e][d0 + 1] = s.y;
            tile[mat][e][d0 + 2] = s.z; tile[mat][e][d0 + 3] = s.w;
        }
    }
    __syncthreads();
    int d = tid & 63, ec = tid >> 6;
    float cp = 0.f;
#pragma unroll
    for (int i = 0; i < 16; i++) cp += tile[1][ec * 16 + i][d];
    cred[ec][d] = cp;
#pragma unroll
    for (int mat = 0; mat < 2; mat++) {
        u16x8 p0, p1;
#pragma unroll
        for (int i = 0; i < 8; i++) {
            p0[i] = f2bf(tile[mat][ec * 16 + i][d]);
            p1[i] = f2bf(tile[mat][ec * 16 + 8 + i][d]);
        }
        u16* dst = (u16*)(ws + (mat ? WS_CTB : WS_MTB)) + (size_t)hq * 4096 + d * 64 + ec * 16;
        *(u16x8*)dst = p0;
        *(u16x8*)(dst + 8) = p1;
    }
    __syncthreads();
    if (tid < 64)
        ws[WS_COLC + (size_t)hq * 64 + tid] =
            cred[0][tid] + cred[1][tid] + cred[2][tid] + cred[3][tid];
}

// ---- K5 (MFMA): out_attn = c1*inv*(fq@M) + c2*(fq@C - qm*colC)  bf16 out ---
__global__ __launch_bounds__(256) void k_apply(float* __restrict__ ws) {
    int nt = blockIdx.x, hq = blockIdx.y;
    int h = hq >> 3, qg = hq & 7;
    __shared__ u16 mt[2][4096];                // swizzled M^T, C^T (8KB each)
    __shared__ float invqm[256][2];
    __shared__ u16 outs[256][66];              // +2 pad
    int tid = threadIdx.x, wid = tid >> 6, lane = tid & 63;
    int i15 = lane & 15, q4 = lane >> 4;
#pragma unroll
    for (int mat = 0; mat < 2; mat++) {
        const u16* src = (const u16*)(ws + (mat ? WS_CTB : WS_MTB)) + (size_t)hq * 4096;
#pragma unroll
        for (int it = 0; it < 2; it++) {
            int i = tid + it * 256;            // 16B chunk id, 512 total
            int d = i >> 3, c8 = i & 7;
            u16x8 v = *(const u16x8*)(src + i * 8);
            int byte = d * 128 + ((c8 * 16) ^ ((d & 7) << 4));
            *(u16x8*)((char*)&mt[mat][0] + byte) = v;
        }
    }
    int R0 = nt * 256;
    invqm[tid][0] = ws[WS_INVNQ + (size_t)hq * 1024 + R0 + tid];
    invqm[tid][1] = ws[WS_QMEAN + (size_t)hq * 1024 + R0 + tid];
    float wv = ws[WS_WGATE + h];
    float c1 = 1.f - wv, c2 = wv * (1.f / 64.f);
    float colc[4];
#pragma unroll
    for (int fn = 0; fn < 4; fn++)
        colc[fn] = ws[WS_COLC + (size_t)hq * 64 + fn * 16 + i15];
    __syncthreads();
    const u16* fq = (const u16*)(ws + WS_FQ) + (size_t)hq * 65536 +
                    (size_t)(R0 + wid * 64) * 64;
    floatx4 aM[4][4], aC[4][4];
#pragma unroll
    for (int i = 0; i < 4; i++)
#pragma unroll
        for (int j = 0; j < 4; j++) {
            aM[i][j] = (floatx4){0.f, 0.f, 0.f, 0.f};
            aC[i][j] = (floatx4){0.f, 0.f, 0.f, 0.f};
        }
#pragma unroll
    for (int ks = 0; ks < 2; ks++) {
        short8 a[4], bM[4], bC[4];
#pragma unroll
        for (int f = 0; f < 4; f++)
            a[f] = *(const short8*)(fq + (size_t)(f * 16 + i15) * 64 + q4 * 8 + ks * 32);
#pragma unroll
        for (int f = 0; f < 4; f++) {
            int col = f * 16 + i15;
            int byte = col * 128 + ((q4 * 16 + ks * 64) ^ ((col & 7) << 4));
            bM[f] = *(const short8*)((char*)&mt[0][0] + byte);
            bC[f] = *(const short8*)((char*)&mt[1][0] + byte);
        }
#pragma unroll
        for (int fm = 0; fm < 4; fm++)
#pragma unroll
            for (int fn = 0; fn < 4; fn++) {
                aM[fm][fn] = __builtin_amdgcn_mfma_f32_16x16x32_bf16(
                    a[fm], bM[fn], aM[fm][fn], 0, 0, 0);
                aC[fm][fn] = __builtin_amdgcn_mfma_f32_16x16x32_bf16(
                    a[fm], bC[fn], aC[fm][fn], 0, 0, 0);
            }
    }
#pragma unroll
    for (int fm = 0; fm < 4; fm++)
#pragma unroll
        for (int reg = 0; reg < 4; reg++) {
            int rloc = wid * 64 + fm * 16 + q4 * 4 + reg;
            float iv = invqm[rloc][0], qmv = invqm[rloc][1];
#pragma unroll
            for (int fn = 0; fn < 4; fn++) {
                float val = c1 * iv * aM[fm][fn][reg] +
                            c2 * (aC[fm][fn][reg] - qmv * colc[fn]);
                outs[rloc][fn * 16 + i15] = f2bf(val);
            }
        }
    __syncthreads();
    u16* oat = (u16*)(ws + WS_OATT);
#pragma unroll
    for (int it = 0; it < 8; it++) {
        int c = tid + it * 256;                // 16B chunk id, 2048 total
        int row = c >> 3, c8 = (c & 7) * 8;
        u16x8 v = *(const u16x8*)&outs[row][c8];
        *(u16x8*)(oat + ((size_t)qg * 1024 + R0 + row) * 512 + h * 64 + c8) = v;
    }
}

// ---------------- host launch ----------------
extern "C" void kernel_launch(void* const* d_in, const int* in_sizes, int n_in,
                              void* d_out, int out_size, void* d_ws, size_t ws_size,
                              hipStream_t stream) {
    (void)in_sizes; (void)n_in; (void)out_size; (void)ws_size;
    const float* q = (const float*)d_in[0];
    const float* k = (const float*)d_in[1];
    const float* v = (const float*)d_in[2];
    const float* ln_g = (const float*)d_in[3];
    const float* ln_b = (const float*)d_in[4];
    const float* w_in = (const float*)d_in[5];
    const float* p_w1 = (const float*)d_in[6];
    const float* p_b1 = (const float*)d_in[7];
    const float* p_ln_g = (const float*)d_in[8];
    const float* p_ln_b = (const float*)d_in[9];
    const float* p_w2 = (const float*)d_in[10];
    const float* p_b2 = (const float*)d_in[11];
    const float* w_out = (const float*)d_in[12];
    const float* b_out = (const float*)d_in[13];
    float* ws = (float*)d_ws;
    float* out = (float*)d_out;

    k_lnstats<<<6144, 256, 0, stream>>>(q, k, v, ws);
    k_prep_t<1><<<dim3(8, 8), 256, 0, stream>>>(w_in, ln_g, (u16*)(ws + WS_WPT), ws + WS_WTF32);
    k_prep_t<0><<<dim3(8, 8), 256, 0, stream>>>(w_out, nullptr, (u16*)(ws + WS_WOT), nullptr);
    k_prep_u<<<128, 256, 0, stream>>>(ln_g, ln_b, ws);
    k_gemm<0, 96><<<dim3(4, 192), 512, 0, stream>>>((const u16*)(ws + WS_XBF),
                                                    (const u16*)(ws + WS_WPT), ws, nullptr, nullptr);
    k_gatered<<<dim3(8, 2), 256, 0, stream>>>(ws);
    k_gate<<<1, 256, 0, stream>>>(p_w1, p_b1, p_ln_g, p_ln_b, p_w2, p_b2, ws);
    k_mc<<<dim3(8, 64), 256, 0, stream>>>(ws);
    k_mcred<<<64, 256, 0, stream>>>(ws);
    k_apply<<<dim3(4, 64), 256, 0, stream>>>(ws);
    k_gemm<1, 32><<<dim3(4, 64), 512, 0, stream>>>((const u16*)(ws + WS_OATT),
                                                   (const u16*)(ws + WS_WOT), ws, out, b_out);
}

// Round 10
// 120.854 us; speedup vs baseline: 1.2114x; 1.0261x over previous
//
#include <hip/hip_runtime.h>
#include <cstdint>

// ---------------- problem constants ----------------
// QG=8, N=1024, DIM=512, H=8, D=64; rows/tensor=8192; HQ=64
// Gram fragment layout per hq ([4 blk16][32 kb][16 i15][4 q4][8] u16):
//   element (n, x) at blk(x>>4)*16384 + (n>>5)*512 + (x&15)*32 + ((n>>3)&3)*8 + (n&7)

typedef unsigned short u16;
typedef unsigned int u32;
typedef __attribute__((ext_vector_type(8))) unsigned short u16x8;
typedef __attribute__((ext_vector_type(4))) unsigned short u16x4;
typedef __attribute__((ext_vector_type(8))) short short8;
typedef __attribute__((ext_vector_type(4))) float floatx4;

// ---------------- workspace layout (float offsets) ----------------
#define WS_XBF     0LL          // bf16 [24576][512]  (q,k,v stacked, row-major)
#define WS_OATT    4194304LL    // bf16 [8192][512]   (aliases XBF tail)
#define WS_WPT     6291456LL    // bf16 W'T [512][512]
#define WS_WOT     6422528LL    // bf16 w_outT [512][512]
#define WS_U       6553600LL    // f32 [512]  g@W_in
#define WS_CB      6554112LL    // f32 [512]  b@W_in
#define WS_LNST    6554624LL    // f32 [24576][2] (mu, rsigma)
#define WS_FQ      6603776LL    // bf16 [64 hq][1024 n][64 d] row-major
#define WS_FKTS    8700928LL    // bf16 Gram frag per hq (K scaled by 1/|k|)
#define WS_FKTC    10798080LL   // bf16 Gram frag (K centered)
#define WS_FVT     12895232LL   // bf16 Gram frag (V)
#define WS_INVNQ   14992384LL   // f32 [64][1024]
#define WS_INVNK   15057920LL   // (written, unused downstream)
#define WS_QMEAN   15123456LL
#define WS_KMEAN   15188992LL   // (written, unused downstream)
#define WS_COLP    15254528LL   // f32 [2][64][8][64][2] (sum, sumsq)
#define WS_WGATE   15385600LL   // f32 [8] (+pad)
#define WS_WTF32   15385664LL   // f32 WT [512][512] (prep-phase only)
#define WS_GSUM    15385664LL   // f32 (gatered->gate only)
#define WS_MTB     15385664LL   // bf16 M^T [64 hq][64 d][64 e] (mc->apply)
#define WS_CTB     15516736LL   // bf16 C^T
#define WS_COLC    15647808LL   // f32 [64][64] colsum of C
// end = 15651904 floats = 62.6 MB

__device__ __forceinline__ float wsum(float v) {
#pragma unroll
    for (int m = 32; m; m >>= 1) v += __shfl_xor(v, m, 64);
    return v;
}
__device__ __forceinline__ u16 f2bf(float f) {
    u32 u = __float_as_uint(f);
    u32 r = u + 0x7fffu + ((u >> 16) & 1u);
    return (u16)(r >> 16);
}
__device__ __forceinline__ float bf2f(u16 u) {
    return __uint_as_float(((u32)u) << 16);
}

// ---------------- K0: LN row stats over DIM=512 + bf16 copy ----------------
__global__ __launch_bounds__(256) void k_lnstats(
    const float* __restrict__ q, const float* __restrict__ k,
    const float* __restrict__ v, float* __restrict__ ws) {
    int wid = threadIdx.x >> 6, lane = threadIdx.x & 63;
    int row = blockIdx.x * 4 + wid;            // 0..24575
    int t = row >> 13, r = row & 8191;
    const float* src = (t == 0) ? q : ((t == 1) ? k : v);
    const float4* p = (const float4*)(src + (size_t)r * 512) + lane * 2;
    float4 a = p[0], b = p[1];
    u16x8 o;
    o[0] = f2bf(a.x); o[1] = f2bf(a.y); o[2] = f2bf(a.z); o[3] = f2bf(a.w);
    o[4] = f2bf(b.x); o[5] = f2bf(b.y); o[6] = f2bf(b.z); o[7] = f2bf(b.w);
    *(u16x8*)((u16*)(ws + WS_XBF) + (size_t)row * 512 + lane * 8) = o;
    float s = a.x + a.y + a.z + a.w + b.x + b.y + b.z + b.w;
    float ss = a.x * a.x + a.y * a.y + a.z * a.z + a.w * a.w +
               b.x * b.x + b.y * b.y + b.z * b.z + b.w * b.w;
    s = wsum(s); ss = wsum(ss);
    if (lane == 0) {
        float mu = s * (1.f / 512.f);
        float var = ss * (1.f / 512.f) - mu * mu;
        ws[WS_LNST + (size_t)row * 2] = mu;
        ws[WS_LNST + (size_t)row * 2 + 1] = rsqrtf(var + 1e-5f);
    }
}

// ---------------- prep: transposed (scaled) bf16 weights ----------------
template <int SCALE>
__global__ __launch_bounds__(256) void k_prep_t(
    const float* __restrict__ W, const float* __restrict__ g,
    u16* __restrict__ Tb, float* __restrict__ Tf) {
    __shared__ float tile[64][65];
    int k0 = blockIdx.x * 64, j0 = blockIdx.y * 64;
    int tid = threadIdx.x;
    int c = (tid & 15) * 4, r0 = tid >> 4;
#pragma unroll
    for (int p = 0; p < 4; p++) {
        int r = r0 + p * 16;
        *(float4*)&tile[r][c] = *(const float4*)(W + (size_t)(k0 + r) * 512 + j0 + c);
    }
    __syncthreads();
    int kc = (tid & 15) * 4, jr0 = tid >> 4;
#pragma unroll
    for (int p = 0; p < 4; p++) {
        int jr = jr0 + p * 16;
        float v0 = tile[kc + 0][jr], v1 = tile[kc + 1][jr];
        float v2 = tile[kc + 2][jr], v3 = tile[kc + 3][jr];
        if (SCALE) {
            *(float4*)(Tf + (size_t)(j0 + jr) * 512 + k0 + kc) = (float4){v0, v1, v2, v3};
            v0 *= g[k0 + kc + 0]; v1 *= g[k0 + kc + 1];
            v2 *= g[k0 + kc + 2]; v3 *= g[k0 + kc + 3];
        }
        u16x4 ob = {f2bf(v0), f2bf(v1), f2bf(v2), f2bf(v3)};
        *(u16x4*)(Tb + (size_t)(j0 + jr) * 512 + k0 + kc) = ob;
    }
}

// ---------------- prep2: u = g@W, cb = b@W (from WT f32) ----------------
__global__ __launch_bounds__(256) void k_prep_u(
    const float* __restrict__ g, const float* __restrict__ b, float* __restrict__ ws) {
    int wid = threadIdx.x >> 6, lane = threadIdx.x & 63;
    int j = blockIdx.x * 4 + wid;              // 0..511
    const float* Tf = ws + WS_WTF32 + (size_t)j * 512;
    float su = 0.f, sc = 0.f;
#pragma unroll
    for (int m = 0; m < 8; m++) {
        int k = lane * 8 + m;
        float w = Tf[k];
        su += g[k] * w; sc += b[k] * w;
    }
    su = wsum(su); sc = wsum(sc);
    if (lane == 0) { ws[WS_U + j] = su; ws[WS_CB + j] = sc; }
}

// ---------------- bf16 MFMA GEMM, 128x128 tile, BK=32, 8 waves -------------
// K-loop: UNCHANGED round-8 proven structure (4-buf LDS, depth-3 prefetch,
// counted vmcnt, rotation swizzle, XCD-bijective block swizzle).
// MODE 0 (proj): vals kept in acc; after fused stats, per-t writes:
//   t=0 FQ row-major; t=1 FKTs/FKTc Gram frag (inv/mean folded); t=2 FVT frag.
// MODE 1 (out): +bias, f32 row-major.  CPX = gridblocks/8.
template <int MODE, int CPX>
__global__ __launch_bounds__(512, 4) void k_gemm(
    const u16* __restrict__ A, const u16* __restrict__ B,
    float* __restrict__ ws, float* __restrict__ out, const float* __restrict__ bias) {
    __shared__ char smem[65536];               // 4 bufs x (A 8K + B 8K)
    int tid = threadIdx.x;
    int wid = tid >> 6, lane = tid & 63;
    int i15 = lane & 15, q4 = lane >> 4;
    int wm = wid >> 2, wn = wid & 3;
    int flat = blockIdx.x + (blockIdx.y << 2);
    int swz = (flat & 7) * CPX + (flat >> 3);
    int c0 = (swz & 3) * 128, m0 = (swz >> 2) * 128;

    floatx4 acc[4][2];
#pragma unroll
    for (int i = 0; i < 4; i++)
#pragma unroll
        for (int j = 0; j < 2; j++) acc[i][j] = (floatx4){0.f, 0.f, 0.f, 0.f};

    const u16* gA = A + (size_t)m0 * 512;
    const u16* gB = B + (size_t)c0 * 512;

    auto stage = [&](int ks, int buf) {
        int o = wid * 1024 + lane * 16;        // byte off in 8KB region
        int srow = o >> 6, s = (o >> 4) & 3;
        int cch = (s - (srow >> 1)) & 3;       // inverse rotation
        const u16* ga = gA + (size_t)srow * 512 + ks * 32 + cch * 8;
        const u16* gb = gB + (size_t)srow * 512 + ks * 32 + cch * 8;
        char* la = smem + buf * 16384 + wid * 1024;
        char* lb = smem + buf * 16384 + 8192 + wid * 1024;
        __builtin_amdgcn_global_load_lds(
            (const __attribute__((address_space(1))) void*)ga,
            (__attribute__((address_space(3))) void*)la, 16, 0, 0);
        __builtin_amdgcn_global_load_lds(
            (const __attribute__((address_space(1))) void*)gb,
            (__attribute__((address_space(3))) void*)lb, 16, 0, 0);
    };

    stage(0, 0);
    stage(1, 1);
    stage(2, 2);
    __builtin_amdgcn_sched_barrier(0);
#pragma unroll
    for (int ks = 0; ks < 16; ks++) {
        __builtin_amdgcn_sched_barrier(0);
        if (ks <= 13)      asm volatile("s_waitcnt vmcnt(4)" ::: "memory");
        else if (ks == 14) asm volatile("s_waitcnt vmcnt(2)" ::: "memory");
        else               asm volatile("s_waitcnt vmcnt(0)" ::: "memory");
        __builtin_amdgcn_s_barrier();
        __builtin_amdgcn_sched_barrier(0);
        if (ks + 3 < 16) stage(ks + 3, (ks + 3) & 3);   // post-barrier: safe
        __builtin_amdgcn_sched_barrier(0);
        int buf = ks & 3;
        short8 a[4], b[2];
#pragma unroll
        for (int f = 0; f < 4; f++) {
            int ra = wm * 64 + f * 16 + i15;
            int sa = (q4 + (ra >> 1)) & 3;     // rotation swizzle
            a[f] = *(const short8*)(smem + buf * 16384 + ra * 64 + sa * 16);
        }
#pragma unroll
        for (int f = 0; f < 2; f++) {
            int rb = wn * 32 + f * 16 + i15;
            int sb = (q4 + (rb >> 1)) & 3;
            b[f] = *(const short8*)(smem + buf * 16384 + 8192 + rb * 64 + sb * 16);
        }
#pragma unroll
        for (int fm = 0; fm < 4; fm++)
#pragma unroll
            for (int fn = 0; fn < 2; fn++)
                acc[fm][fn] = __builtin_amdgcn_mfma_f32_16x16x32_bf16(
                    a[fm], b[fn], acc[fm][fn], 0, 0, 0);
    }

    if constexpr (MODE == 1) {
#pragma unroll
        for (int fm = 0; fm < 4; fm++)
#pragma unroll
            for (int reg = 0; reg < 4; reg++) {
                int gm = m0 + wm * 64 + fm * 16 + q4 * 4 + reg;
#pragma unroll
                for (int fn = 0; fn < 2; fn++) {
                    int gc = c0 + wn * 32 + fn * 16 + i15;
                    out[(size_t)gm * 512 + gc] = acc[fm][fn][reg] + bias[gc];
                }
            }
    } else {
        __syncthreads();                       // staging dead; reuse as scratch
        float2* rowred = (float2*)smem;        // [8 waves][64 rows]
        float2* colred = (float2*)(smem + 4096);  // [8 waves][32 cols]
        float2* lnfin  = (float2*)(smem + 6144);  // [2 hp][128 rows] (inv,mean)
        int t = m0 >> 13;
        int nbase = m0 & 1023;
        int rr = m0 & 8191, qg = rr >> 10, nblk = (rr >> 7) & 7;
        int hp = wn >> 1;
        int h = (c0 >> 6) + hp, hq = h * 8 + qg;
        int dwn = (wn & 1) * 32;
        float u_[2], cb_[2];
#pragma unroll
        for (int fn = 0; fn < 2; fn++) {
            int gc = c0 + wn * 32 + fn * 16 + i15;
            u_[fn] = ws[WS_U + gc]; cb_[fn] = ws[WS_CB + gc];
        }
        float csum[2] = {0, 0}, css[2] = {0, 0};
#pragma unroll
        for (int fm = 0; fm < 4; fm++) {
#pragma unroll
            for (int reg = 0; reg < 4; reg++) {
                int gm = m0 + wm * 64 + fm * 16 + q4 * 4 + reg;
                float2 st = *(const float2*)(ws + WS_LNST + (size_t)gm * 2);
                float mu = st.x, rs = st.y;
                float r1 = 0.f, r2 = 0.f;
#pragma unroll
                for (int fn = 0; fn < 2; fn++) {
                    float val = rs * acc[fm][fn][reg] - rs * mu * u_[fn] + cb_[fn];
                    acc[fm][fn][reg] = val;    // keep for per-t writes
                    r1 += val; r2 += val * val;
                    csum[fn] += val; css[fn] += val * val;
                }
                if (t < 2) {
#pragma unroll
                    for (int m = 1; m < 16; m <<= 1) {
                        r1 += __shfl_xor(r1, m, 64);
                        r2 += __shfl_xor(r2, m, 64);
                    }
                    if (i15 == fm * 4 + reg)
                        rowred[(size_t)wid * 64 + fm * 16 + q4 * 4 + reg] = (float2){r1, r2};
                }
            }
        }
        if (t < 2) {
#pragma unroll
            for (int fn = 0; fn < 2; fn++) {
                float s1 = csum[fn], s2 = css[fn];
                s1 += __shfl_xor(s1, 16, 64); s1 += __shfl_xor(s1, 32, 64);
                s2 += __shfl_xor(s2, 16, 64); s2 += __shfl_xor(s2, 32, 64);
                if (q4 == fn) colred[(size_t)wid * 32 + fn * 16 + i15] = (float2){s1, s2};
            }
        }
        __syncthreads();
        if (t < 2) {
            float* invn = ws + (t ? WS_INVNK : WS_INVNQ);
            float* mean = ws + (t ? WS_KMEAN : WS_QMEAN);
            if (tid < 256) {                   // 2 wm x 2 headpair x 64 rows
                int wmf = tid >> 7, p = (tid >> 6) & 1, r = tid & 63;
                float2 aa = rowred[(size_t)(wmf * 4 + 2 * p) * 64 + r];
                float2 bb = rowred[(size_t)(wmf * 4 + 2 * p + 1) * 64 + r];
                float s1 = aa.x + bb.x, s2 = aa.y + bb.y;
                float iv = rsqrtf(s2), mn = s1 * (1.f / 64.f);
                int n = nbase + wmf * 64 + r;
                int hhq = ((c0 >> 6) + p) * 8 + qg;
                invn[(size_t)hhq * 1024 + n] = iv;
                mean[(size_t)hhq * 1024 + n] = mn;
                lnfin[p * 128 + wmf * 64 + r] = (float2){iv, mn};
            } else if (tid < 384) {            // 2 headpair x 64 cols
                int tt = tid - 256;
                int p = tt >> 6, d = tt & 63;
                int wnn = 2 * p + (d >> 5), loc = d & 31;
                float2 aa = colred[(size_t)(0 * 4 + wnn) * 32 + loc];
                float2 bb = colred[(size_t)(1 * 4 + wnn) * 32 + loc];
                int hhq = ((c0 >> 6) + p) * 8 + qg;
                *(float2*)(ws + WS_COLP +
                           (size_t)(((t * 64 + hhq) * 8 + nblk) * 64 + d) * 2) =
                    (float2){aa.x + bb.x, aa.y + bb.y};
            }
        }
        __syncthreads();
        if (t == 0) {                          // FQ row-major [hq][n][64]
            u16* fout = (u16*)(ws + WS_FQ) + (size_t)hq * 65536;
#pragma unroll
            for (int fm = 0; fm < 4; fm++)
#pragma unroll
                for (int reg = 0; reg < 4; reg++) {
                    int n = nbase + wm * 64 + fm * 16 + q4 * 4 + reg;
#pragma unroll
                    for (int fn = 0; fn < 2; fn++)
                        fout[(size_t)n * 64 + dwn + fn * 16 + i15] =
                            f2bf(acc[fm][fn][reg]);
                }
        } else if (t == 1) {                   // FKTs/FKTc Gram frag
            u16* fs = (u16*)(ws + WS_FKTS) + (size_t)hq * 65536;
            u16* fc = (u16*)(ws + WS_FKTC) + (size_t)hq * 65536;
#pragma unroll
            for (int fn = 0; fn < 2; fn++) {
                int eoff = ((wn & 1) * 2 + fn) * 16384 + i15 * 32;
#pragma unroll
                for (int fm = 0; fm < 4; fm++) {
                    int n0l = wm * 64 + fm * 16 + q4 * 4;
                    int n0 = nbase + n0l;
                    int off = eoff + (n0 >> 5) * 512 + ((n0 >> 3) & 3) * 8 + (n0 & 7);
                    u16x4 vs, vc;
#pragma unroll
                    for (int reg = 0; reg < 4; reg++) {
                        float2 im = lnfin[hp * 128 + n0l + reg];
                        float val = acc[fm][fn][reg];
                        vs[reg] = f2bf(val * im.x);
                        vc[reg] = f2bf(val - im.y);
                    }
                    *(u16x4*)(fs + off) = vs;
                    *(u16x4*)(fc + off) = vc;
                }
            }
        } else {                               // FVT Gram frag
            u16* fv = (u16*)(ws + WS_FVT) + (size_t)hq * 65536;
#pragma unroll
            for (int fn = 0; fn < 2; fn++) {
                int doff = ((wn & 1) * 2 + fn) * 16384 + i15 * 32;
#pragma unroll
                for (int fm = 0; fm < 4; fm++) {
                    int n0 = nbase + wm * 64 + fm * 16 + q4 * 4;
                    int off = doff + (n0 >> 5) * 512 + ((n0 >> 3) & 3) * 8 + (n0 & 7);
                    u16x4 v4;
#pragma unroll
                    for (int reg = 0; reg < 4; reg++) v4[reg] = f2bf(acc[fm][fn][reg]);
                    *(u16x4*)(fv + off) = v4;
                }
            }
        }
    }
}

// ---------------- K3a: parallel COLP reduction -> GSUM[2][8][64][2] --------
__global__ __launch_bounds__(256) void k_gatered(float* __restrict__ ws) {
    int h = blockIdx.x, t = blockIdx.y;
    int tid = threadIdx.x;
    int c = tid & 127, rg = tid >> 7;
    const float* base = ws + WS_COLP + ((size_t)(t * 64 + h * 8) * 8) * 128;
    float s = 0.f;
#pragma unroll 8
    for (int r = rg * 32; r < rg * 32 + 32; r++) s += base[(size_t)r * 128 + c];
    __shared__ float red[2][128];
    red[rg][c] = s;
    __syncthreads();
    if (tid < 128)
        ws[WS_GSUM + ((size_t)t * 8 + h) * 128 + tid] = red[0][tid] + red[1][tid];
}

// ---------------- K3b: gate MLP + variance penalty ----------------
__global__ __launch_bounds__(256) void k_gate(
    const float* __restrict__ pw1, const float* __restrict__ pb1,
    const float* __restrict__ plg, const float* __restrict__ plb,
    const float* __restrict__ pw2, const float* __restrict__ pb2,
    float* __restrict__ ws) {
    __shared__ float w1[128][64];
    __shared__ float gs[2][8][128];
    int tid = threadIdx.x, wid = tid >> 6, lane = tid & 63;
    for (int r = wid; r < 128; r += 4) w1[r][lane] = pw1[r * 64 + lane];
    for (int i = tid; i < 2048; i += 256) ((float*)gs)[i] = ws[WS_GSUM + i];
    __syncthreads();
    if (wid != 0) return;
    float Sq = 0, SSq = 0, Sk = 0, SSk = 0;
#pragma unroll
    for (int h = 0; h < 8; h++) {
        Sq += gs[0][h][lane * 2];  SSq += gs[0][h][lane * 2 + 1];
        Sk += gs[1][h][lane * 2];  SSk += gs[1][h][lane * 2 + 1];
    }
    const float NR = 65536.f;
    float stdq = sqrtf((SSq - Sq * Sq / NR) / (NR - 1.f) + 1e-4f);
    float stdk = sqrtf((SSk - Sk * Sk / NR) / (NR - 1.f) + 1e-4f);
    float vpen = (wsum(fmaxf(1.f - stdq, 0.f)) + wsum(fmaxf(1.f - stdk, 0.f))) * (1.f / 64.f);
    float gammav = plg[lane], betav = plb[lane], w2v = pw2[lane];
    for (int h = 0; h < 8; h++) {
        float y = pb1[lane];
#pragma unroll 8
        for (int i = 0; i < 64; i++) {
            y = fmaf(gs[0][h][i * 2] * (1.f / 8192.f), w1[i][lane], y);
            y = fmaf(gs[1][h][i * 2] * (1.f / 8192.f), w1[64 + i][lane], y);
        }
        float mu = wsum(y) * (1.f / 64.f);
        float dv = y - mu;
        float var = wsum(dv * dv) * (1.f / 64.f);
        float z = dv * rsqrtf(var + 1e-5f) * gammav + betav;
        float r = fmaxf(z, 0.f);
        float sdot = wsum(r * w2v);
        if (lane == 0) {
            float wv = 1.f / (1.f + expf(-(sdot + pb2[0])));
            ws[WS_WGATE + h] = wv / (1.f + vpen);
        }
    }
}

// ------- K4 (MFMA): M,C Gram matrices per hq, K=1024, barrier-free ---------
// A-frags from FKTs/FKTc, B-frags from FVT (both Gram frag layout, coalesced).
// 4 waves split output 2x2; epilogue: LDS transpose -> bf16 M^T/C^T + colC.
__global__ __launch_bounds__(256) void k_mc(float* __restrict__ ws) {
    int hq = blockIdx.x;
    int tid = threadIdx.x, wid = tid >> 6, lane = tid & 63;
    int i15 = lane & 15, q4 = lane >> 4;
    int we = wid >> 1, wd = wid & 1;
    const u16* fs = (const u16*)(ws + WS_FKTS) + (size_t)hq * 65536;
    const u16* fc = (const u16*)(ws + WS_FKTC) + (size_t)hq * 65536;
    const u16* fv = (const u16*)(ws + WS_FVT) + (size_t)hq * 65536;
    floatx4 aM[2][2], aC[2][2];
#pragma unroll
    for (int f = 0; f < 2; f++)
#pragma unroll
        for (int g = 0; g < 2; g++) {
            aM[f][g] = (floatx4){0.f, 0.f, 0.f, 0.f};
            aC[f][g] = (floatx4){0.f, 0.f, 0.f, 0.f};
        }
#pragma unroll 8
    for (int ks = 0; ks < 32; ks++) {
        short8 as_[2], ac_[2], b_[2];
#pragma unroll
        for (int f = 0; f < 2; f++) {
            int off = (we * 2 + f) * 16384 + ks * 512 + i15 * 32 + q4 * 8;
            as_[f] = *(const short8*)(fs + off);
            ac_[f] = *(const short8*)(fc + off);
        }
#pragma unroll
        for (int g = 0; g < 2; g++)
            b_[g] = *(const short8*)(fv + (wd * 2 + g) * 16384 + ks * 512 +
                                     i15 * 32 + q4 * 8);
#pragma unroll
        for (int f = 0; f < 2; f++)
#pragma unroll
            for (int g = 0; g < 2; g++) {
                aM[f][g] = __builtin_amdgcn_mfma_f32_16x16x32_bf16(
                    as_[f], b_[g], aM[f][g], 0, 0, 0);
                aC[f][g] = __builtin_amdgcn_mfma_f32_16x16x32_bf16(
                    ac_[f], b_[g], aC[f][g], 0, 0, 0);
            }
    }
    __shared__ float tile[2][64][65];
    __shared__ float cred[4][64];
#pragma unroll
    for (int f = 0; f < 2; f++)
#pragma unroll
        for (int g = 0; g < 2; g++)
#pragma unroll
            for (int reg = 0; reg < 4; reg++) {
                int e = we * 32 + f * 16 + q4 * 4 + reg;
                int d = wd * 32 + g * 16 + i15;
                tile[0][e][d] = aM[f][g][reg];
                tile[1][e][d] = aC[f][g][reg];
            }
    __syncthreads();
    int d = tid & 63, ec = tid >> 6;
    float cp = 0.f;
#pragma unroll
    for (int i = 0; i < 16; i++) cp += tile[1][ec * 16 + i][d];
    cred[ec][d] = cp;
#pragma unroll
    for (int mat = 0; mat < 2; mat++) {
        u16x8 p0, p1;
#pragma unroll
        for (int i = 0; i < 8; i++) {
            p0[i] = f2bf(tile[mat][ec * 16 + i][d]);
            p1[i] = f2bf(tile[mat][ec * 16 + 8 + i][d]);
        }
        u16* dst = (u16*)(ws + (mat ? WS_CTB : WS_MTB)) + (size_t)hq * 4096 + d * 64 + ec * 16;
        *(u16x8*)dst = p0;
        *(u16x8*)(dst + 8) = p1;
    }
    __syncthreads();
    if (tid < 64)
        ws[WS_COLC + (size_t)hq * 64 + tid] =
            cred[0][tid] + cred[1][tid] + cred[2][tid] + cred[3][tid];
}

// ---- K5 (MFMA): out_attn = c1*inv*(fq@M) + c2*(fq@C - qm*colC)  bf16 out ---
__global__ __launch_bounds__(256) void k_apply(float* __restrict__ ws) {
    int nt = blockIdx.x, hq = blockIdx.y;
    int h = hq >> 3, qg = hq & 7;
    __shared__ u16 mt[2][4096];                // swizzled M^T, C^T (8KB each)
    __shared__ float invqm[256][2];
    __shared__ u16 outs[256][66];              // +2 pad
    int tid = threadIdx.x, wid = tid >> 6, lane = tid & 63;
    int i15 = lane & 15, q4 = lane >> 4;
#pragma unroll
    for (int mat = 0; mat < 2; mat++) {
        const u16* src = (const u16*)(ws + (mat ? WS_CTB : WS_MTB)) + (size_t)hq * 4096;
#pragma unroll
        for (int it = 0; it < 2; it++) {
            int i = tid + it * 256;            // 16B chunk id, 512 total
            int d = i >> 3, c8 = i & 7;
            u16x8 v = *(const u16x8*)(src + i * 8);
            int byte = d * 128 + ((c8 * 16) ^ ((d & 7) << 4));
            *(u16x8*)((char*)&mt[mat][0] + byte) = v;
        }
    }
    int R0 = nt * 256;
    invqm[tid][0] = ws[WS_INVNQ + (size_t)hq * 1024 + R0 + tid];
    invqm[tid][1] = ws[WS_QMEAN + (size_t)hq * 1024 + R0 + tid];
    float wv = ws[WS_WGATE + h];
    float c1 = 1.f - wv, c2 = wv * (1.f / 64.f);
    float colc[4];
#pragma unroll
    for (int fn = 0; fn < 4; fn++)
        colc[fn] = ws[WS_COLC + (size_t)hq * 64 + fn * 16 + i15];
    __syncthreads();
    const u16* fq = (const u16*)(ws + WS_FQ) + (size_t)hq * 65536 +
                    (size_t)(R0 + wid * 64) * 64;
    floatx4 aM[4][4], aC[4][4];
#pragma unroll
    for (int i = 0; i < 4; i++)
#pragma unroll
        for (int j = 0; j < 4; j++) {
            aM[i][j] = (floatx4){0.f, 0.f, 0.f, 0.f};
            aC[i][j] = (floatx4){0.f, 0.f, 0.f, 0.f};
        }
#pragma unroll
    for (int ks = 0; ks < 2; ks++) {
        short8 a[4], bM[4], bC[4];
#pragma unroll
        for (int f = 0; f < 4; f++)
            a[f] = *(const short8*)(fq + (size_t)(f * 16 + i15) * 64 + q4 * 8 + ks * 32);
#pragma unroll
        for (int f = 0; f < 4; f++) {
            int col = f * 16 + i15;
            int byte = col * 128 + ((q4 * 16 + ks * 64) ^ ((col & 7) << 4));
            bM[f] = *(const short8*)((char*)&mt[0][0] + byte);
            bC[f] = *(const short8*)((char*)&mt[1][0] + byte);
        }
#pragma unroll
        for (int fm = 0; fm < 4; fm++)
#pragma unroll
            for (int fn = 0; fn < 4; fn++) {
                aM[fm][fn] = __builtin_amdgcn_mfma_f32_16x16x32_bf16(
                    a[fm], bM[fn], aM[fm][fn], 0, 0, 0);
                aC[fm][fn] = __builtin_amdgcn_mfma_f32_16x16x32_bf16(
                    a[fm], bC[fn], aC[fm][fn], 0, 0, 0);
            }
    }
#pragma unroll
    for (int fm = 0; fm < 4; fm++)
#pragma unroll
        for (int reg = 0; reg < 4; reg++) {
            int rloc = wid * 64 + fm * 16 + q4 * 4 + reg;
            float iv = invqm[rloc][0], qmv = invqm[rloc][1];
#pragma unroll
            for (int fn = 0; fn < 4; fn++) {
                float val = c1 * iv * aM[fm][fn][reg] +
                            c2 * (aC[fm][fn][reg] - qmv * colc[fn]);
                outs[rloc][fn * 16 + i15] = f2bf(val);
            }
        }
    __syncthreads();
    u16* oat = (u16*)(ws + WS_OATT);
#pragma unroll
    for (int it = 0; it < 8; it++) {
        int c = tid + it * 256;                // 16B chunk id, 2048 total
        int row = c >> 3, c8 = (c & 7) * 8;
        u16x8 v = *(const u16x8*)&outs[row][c8];
        *(u16x8*)(oat + ((size_t)qg * 1024 + R0 + row) * 512 + h * 64 + c8) = v;
    }
}

// ---------------- host launch ----------------
extern "C" void kernel_launch(void* const* d_in, const int* in_sizes, int n_in,
                              void* d_out, int out_size, void* d_ws, size_t ws_size,
                              hipStream_t stream) {
    (void)in_sizes; (void)n_in; (void)out_size; (void)ws_size;
    const float* q = (const float*)d_in[0];
    const float* k = (const float*)d_in[1];
    const float* v = (const float*)d_in[2];
    const float* ln_g = (const float*)d_in[3];
    const float* ln_b = (const float*)d_in[4];
    const float* w_in = (const float*)d_in[5];
    const float* p_w1 = (const float*)d_in[6];
    const float* p_b1 = (const float*)d_in[7];
    const float* p_ln_g = (const float*)d_in[8];
    const float* p_ln_b = (const float*)d_in[9];
    const float* p_w2 = (const float*)d_in[10];
    const float* p_b2 = (const float*)d_in[11];
    const float* w_out = (const float*)d_in[12];
    const float* b_out = (const float*)d_in[13];
    float* ws = (float*)d_ws;
    float* out = (float*)d_out;

    k_lnstats<<<6144, 256, 0, stream>>>(q, k, v, ws);
    k_prep_t<1><<<dim3(8, 8), 256, 0, stream>>>(w_in, ln_g, (u16*)(ws + WS_WPT), ws + WS_WTF32);
    k_prep_t<0><<<dim3(8, 8), 256, 0, stream>>>(w_out, nullptr, (u16*)(ws + WS_WOT), nullptr);
    k_prep_u<<<128, 256, 0, stream>>>(ln_g, ln_b, ws);
    k_gemm<0, 96><<<dim3(4, 192), 512, 0, stream>>>((const u16*)(ws + WS_XBF),
                                                    (const u16*)(ws + WS_WPT), ws, nullptr, nullptr);
    k_gatered<<<dim3(8, 2), 256, 0, stream>>>(ws);
    k_gate<<<1, 256, 0, stream>>>(p_w1, p_b1, p_ln_g, p_ln_b, p_w2, p_b2, ws);
    k_mc<<<64, 256, 0, stream>>>(ws);
    k_apply<<<dim3(4, 64), 256, 0, stream>>>(ws);
    k_gemm<1, 32><<<dim3(4, 64), 512, 0, stream>>>((const u16*)(ws + WS_OATT),
                                                   (const u16*)(ws + WS_WOT), ws, out, b_out);
}

// Round 12
// 115.816 us; speedup vs baseline: 1.2641x; 1.0435x over previous
//
#include <hip/hip_runtime.h>
#include <cstdint>

// ---------------- problem constants ----------------
// QG=8, N=1024, DIM=512, H=8, D=64; rows/tensor=8192; HQ=64
// Gram fragment layout per hq ([4 blk16][32 kb][16 i15][4 q4][8] u16):
//   element (n, x) at blk(x>>4)*16384 + (n>>5)*512 + (x&15)*32 + ((n>>3)&3)*8 + (n&7)

typedef unsigned short u16;
typedef unsigned int u32;
typedef __attribute__((ext_vector_type(8))) unsigned short u16x8;
typedef __attribute__((ext_vector_type(4))) unsigned short u16x4;
typedef __attribute__((ext_vector_type(8))) short short8;
typedef __attribute__((ext_vector_type(4))) float floatx4;

// ---------------- workspace layout (float offsets) ----------------
#define WS_XBF     0LL          // bf16 [24576][512]  (q,k,v stacked, row-major)
#define WS_OATT    4194304LL    // bf16 [8192][512]   (aliases XBF tail)
#define WS_WPT     6291456LL    // bf16 W'T [512][512]
#define WS_WOT     6422528LL    // bf16 w_outT [512][512]
#define WS_U       6553600LL    // f32 [512]  g@W_in
#define WS_CB      6554112LL    // f32 [512]  b@W_in
#define WS_LNST    6554624LL    // f32 [24576][2] (mu, rsigma)
#define WS_FQ      6603776LL    // bf16 [64 hq][1024 n][64 d] row-major
#define WS_FKTS    8700928LL    // bf16 Gram frag per hq (K scaled by 1/|k|)
#define WS_FKTC    10798080LL   // bf16 Gram frag (K centered)
#define WS_FVT     12895232LL   // bf16 Gram frag (V)
#define WS_INVNQ   14992384LL   // f32 [64][1024]
#define WS_INVNK   15057920LL   // (written, unused downstream)
#define WS_QMEAN   15123456LL
#define WS_KMEAN   15188992LL   // (written, unused downstream)
#define WS_COLP    15254528LL   // f32 [2][64][8][64][2] (sum, sumsq)
#define WS_WGATE   15385600LL   // f32 [8] (+pad)
#define WS_WTF32   15385664LL   // f32 WT [512][512] (prep-phase only)
#define WS_GSUM    15385664LL   // f32 (gatered->gate only)
#define WS_MTB     15385664LL   // bf16 M^T [64 hq][64 d][64 e] (mc->apply)
#define WS_CTB     15516736LL   // bf16 C^T
#define WS_COLC    15647808LL   // f32 [64][64] colsum of C
// end = 15651904 floats = 62.6 MB

__device__ __forceinline__ float wsum(float v) {
#pragma unroll
    for (int m = 32; m; m >>= 1) v += __shfl_xor(v, m, 64);
    return v;
}
__device__ __forceinline__ u16 f2bf(float f) {
    u32 u = __float_as_uint(f);
    u32 r = u + 0x7fffu + ((u >> 16) & 1u);
    return (u16)(r >> 16);
}
__device__ __forceinline__ float bf2f(u16 u) {
    return __uint_as_float(((u32)u) << 16);
}

// ---------------- K0: LN row stats over DIM=512 + bf16 copy ----------------
__global__ __launch_bounds__(256) void k_lnstats(
    const float* __restrict__ q, const float* __restrict__ k,
    const float* __restrict__ v, float* __restrict__ ws) {
    int wid = threadIdx.x >> 6, lane = threadIdx.x & 63;
    int row = blockIdx.x * 4 + wid;            // 0..24575
    int t = row >> 13, r = row & 8191;
    const float* src = (t == 0) ? q : ((t == 1) ? k : v);
    const float4* p = (const float4*)(src + (size_t)r * 512) + lane * 2;
    float4 a = p[0], b = p[1];
    u16x8 o;
    o[0] = f2bf(a.x); o[1] = f2bf(a.y); o[2] = f2bf(a.z); o[3] = f2bf(a.w);
    o[4] = f2bf(b.x); o[5] = f2bf(b.y); o[6] = f2bf(b.z); o[7] = f2bf(b.w);
    *(u16x8*)((u16*)(ws + WS_XBF) + (size_t)row * 512 + lane * 8) = o;
    float s = a.x + a.y + a.z + a.w + b.x + b.y + b.z + b.w;
    float ss = a.x * a.x + a.y * a.y + a.z * a.z + a.w * a.w +
               b.x * b.x + b.y * b.y + b.z * b.z + b.w * b.w;
    s = wsum(s); ss = wsum(ss);
    if (lane == 0) {
        float mu = s * (1.f / 512.f);
        float var = ss * (1.f / 512.f) - mu * mu;
        ws[WS_LNST + (size_t)row * 2] = mu;
        ws[WS_LNST + (size_t)row * 2 + 1] = rsqrtf(var + 1e-5f);
    }
}

// ---------------- prep: transposed (scaled) bf16 weights ----------------
template <int SCALE>
__global__ __launch_bounds__(256) void k_prep_t(
    const float* __restrict__ W, const float* __restrict__ g,
    u16* __restrict__ Tb, float* __restrict__ Tf) {
    __shared__ float tile[64][65];
    int k0 = blockIdx.x * 64, j0 = blockIdx.y * 64;
    int tid = threadIdx.x;
    int c = (tid & 15) * 4, r0 = tid >> 4;
#pragma unroll
    for (int p = 0; p < 4; p++) {
        int r = r0 + p * 16;
        *(float4*)&tile[r][c] = *(const float4*)(W + (size_t)(k0 + r) * 512 + j0 + c);
    }
    __syncthreads();
    int kc = (tid & 15) * 4, jr0 = tid >> 4;
#pragma unroll
    for (int p = 0; p < 4; p++) {
        int jr = jr0 + p * 16;
        float v0 = tile[kc + 0][jr], v1 = tile[kc + 1][jr];
        float v2 = tile[kc + 2][jr], v3 = tile[kc + 3][jr];
        if (SCALE) {
            *(float4*)(Tf + (size_t)(j0 + jr) * 512 + k0 + kc) = (float4){v0, v1, v2, v3};
            v0 *= g[k0 + kc + 0]; v1 *= g[k0 + kc + 1];
            v2 *= g[k0 + kc + 2]; v3 *= g[k0 + kc + 3];
        }
        u16x4 ob = {f2bf(v0), f2bf(v1), f2bf(v2), f2bf(v3)};
        *(u16x4*)(Tb + (size_t)(j0 + jr) * 512 + k0 + kc) = ob;
    }
}

// ---------------- prep2: u = g@W, cb = b@W (from WT f32) ----------------
__global__ __launch_bounds__(256) void k_prep_u(
    const float* __restrict__ g, const float* __restrict__ b, float* __restrict__ ws) {
    int wid = threadIdx.x >> 6, lane = threadIdx.x & 63;
    int j = blockIdx.x * 4 + wid;              // 0..511
    const float* Tf = ws + WS_WTF32 + (size_t)j * 512;
    float su = 0.f, sc = 0.f;
#pragma unroll
    for (int m = 0; m < 8; m++) {
        int k = lane * 8 + m;
        float w = Tf[k];
        su += g[k] * w; sc += b[k] * w;
    }
    su = wsum(su); sc = wsum(sc);
    if (lane == 0) { ws[WS_U + j] = su; ws[WS_CB + j] = sc; }
}

// ------- K1 (proj, q/k/v fused): 3x A-tiles share one B panel --------------
// Per K-step: stage {Aq,Ak,Av,B} 8KB each (4 glds/wave), 24 MFMA/wave.
// 4 bufs x 32KB = 128KB LDS, depth-3 prefetch, vmcnt(8) steady (4 ops/stage).
// Grid (4,64) = 256 blocks = 1/CU. Epilogue: per-t LN fold + stats + writes
// (t=0 FQ row-major; t=1 FKTs/FKTc Gram frag; t=2 FVT Gram frag).
// NOTE: per-hq row index is m0 & 1023 (round-11 bug: used m0 directly).
template <int CPX>
__global__ __launch_bounds__(512, 2) void k_proj(
    const u16* __restrict__ A, const u16* __restrict__ B, float* __restrict__ ws) {
    __shared__ char smem[131072];              // 4 bufs x {Aq,Ak,Av,B}x8KB
    int tid = threadIdx.x;
    int wid = tid >> 6, lane = tid & 63;
    int i15 = lane & 15, q4 = lane >> 4;
    int wm = wid >> 2, wn = wid & 3;
    int flat = blockIdx.x + (blockIdx.y << 2);
    int swz = (flat & 7) * CPX + (flat >> 3);
    int c0 = (swz & 3) * 128, m0 = (swz >> 2) * 128;   // m0 in 0..8064

    floatx4 acc[3][4][2];
#pragma unroll
    for (int t = 0; t < 3; t++)
#pragma unroll
        for (int i = 0; i < 4; i++)
#pragma unroll
            for (int j = 0; j < 2; j++) acc[t][i][j] = (floatx4){0.f, 0.f, 0.f, 0.f};

    const u16* gB = B + (size_t)c0 * 512;

    auto stage = [&](int ks, int buf) {
        int o = wid * 1024 + lane * 16;        // byte off in 8KB region
        int srow = o >> 6, s = (o >> 4) & 3;
        int cch = (s - (srow >> 1)) & 3;       // inverse rotation
        size_t roff = (size_t)srow * 512 + ks * 32 + cch * 8;
        char* base = smem + buf * 32768 + wid * 1024;
#pragma unroll
        for (int t = 0; t < 3; t++) {
            const u16* ga = A + (size_t)(t * 8192 + m0) * 512 + roff;
            __builtin_amdgcn_global_load_lds(
                (const __attribute__((address_space(1))) void*)ga,
                (__attribute__((address_space(3))) void*)(base + t * 8192), 16, 0, 0);
        }
        __builtin_amdgcn_global_load_lds(
            (const __attribute__((address_space(1))) void*)(gB + roff),
            (__attribute__((address_space(3))) void*)(base + 24576), 16, 0, 0);
    };

    stage(0, 0);
    stage(1, 1);
    stage(2, 2);
    __builtin_amdgcn_sched_barrier(0);
#pragma unroll
    for (int ks = 0; ks < 16; ks++) {
        __builtin_amdgcn_sched_barrier(0);
        // outstanding at wait: stages ks,ks+1,ks+2 = 12 ops; vmcnt(8) -> ks done
        if (ks <= 13)      asm volatile("s_waitcnt vmcnt(8)" ::: "memory");
        else if (ks == 14) asm volatile("s_waitcnt vmcnt(4)" ::: "memory");
        else               asm volatile("s_waitcnt vmcnt(0)" ::: "memory");
        __builtin_amdgcn_s_barrier();
        __builtin_amdgcn_sched_barrier(0);
        if (ks + 3 < 16) stage(ks + 3, (ks + 3) & 3);   // post-barrier: safe
        __builtin_amdgcn_sched_barrier(0);
        char* bb = smem + (ks & 3) * 32768;
        short8 b[2];
#pragma unroll
        for (int f = 0; f < 2; f++) {
            int rb = wn * 32 + f * 16 + i15;
            int sb = (q4 + (rb >> 1)) & 3;     // rotation swizzle
            b[f] = *(const short8*)(bb + 24576 + rb * 64 + sb * 16);
        }
#pragma unroll
        for (int t = 0; t < 3; t++) {
            short8 a[4];
#pragma unroll
            for (int f = 0; f < 4; f++) {
                int ra = wm * 64 + f * 16 + i15;
                int sa = (q4 + (ra >> 1)) & 3;
                a[f] = *(const short8*)(bb + t * 8192 + ra * 64 + sa * 16);
            }
#pragma unroll
            for (int fm = 0; fm < 4; fm++)
#pragma unroll
                for (int fn = 0; fn < 2; fn++)
                    acc[t][fm][fn] = __builtin_amdgcn_mfma_f32_16x16x32_bf16(
                        a[fm], b[fn], acc[t][fm][fn], 0, 0, 0);
        }
    }

    // ---------------- epilogue: per-t LN fold + stats + writes ----------
    float2* rowred = (float2*)smem;            // [8 waves][64 rows]
    float2* colred = (float2*)(smem + 4096);   // [8 waves][32 cols]
    float2* lnfin  = (float2*)(smem + 6144);   // [2 hp][128 rows] (inv,mean)
    int nbase = m0 & 1023;                     // per-hq row base (FIX)
    int qg = m0 >> 10, nblk = (m0 >> 7) & 7;
    int hp = wn >> 1;
    int h = (c0 >> 6) + hp, hq = h * 8 + qg;
    int dwn = (wn & 1) * 32;
    float u_[2], cb_[2];
#pragma unroll
    for (int fn = 0; fn < 2; fn++) {
        int gc = c0 + wn * 32 + fn * 16 + i15;
        u_[fn] = ws[WS_U + gc]; cb_[fn] = ws[WS_CB + gc];
    }
#pragma unroll
    for (int t = 0; t < 3; t++) {
        __syncthreads();                       // scratch free (K-loop / prev t)
        float csum[2] = {0, 0}, css[2] = {0, 0};
#pragma unroll
        for (int fm = 0; fm < 4; fm++) {
#pragma unroll
            for (int reg = 0; reg < 4; reg++) {
                int grow = t * 8192 + m0 + wm * 64 + fm * 16 + q4 * 4 + reg;  // LNST row
                float2 st = *(const float2*)(ws + WS_LNST + (size_t)grow * 2);
                float mu = st.x, rs = st.y;
                float r1 = 0.f, r2 = 0.f;
#pragma unroll
                for (int fn = 0; fn < 2; fn++) {
                    float val = rs * acc[t][fm][fn][reg] - rs * mu * u_[fn] + cb_[fn];
                    acc[t][fm][fn][reg] = val;
                    r1 += val; r2 += val * val;
                    csum[fn] += val; css[fn] += val * val;
                }
                if (t < 2) {
#pragma unroll
                    for (int m = 1; m < 16; m <<= 1) {
                        r1 += __shfl_xor(r1, m, 64);
                        r2 += __shfl_xor(r2, m, 64);
                    }
                    if (i15 == fm * 4 + reg)
                        rowred[(size_t)wid * 64 + fm * 16 + q4 * 4 + reg] = (float2){r1, r2};
                }
            }
        }
        if (t < 2) {
#pragma unroll
            for (int fn = 0; fn < 2; fn++) {
                float s1 = csum[fn], s2 = css[fn];
                s1 += __shfl_xor(s1, 16, 64); s1 += __shfl_xor(s1, 32, 64);
                s2 += __shfl_xor(s2, 16, 64); s2 += __shfl_xor(s2, 32, 64);
                if (q4 == fn) colred[(size_t)wid * 32 + fn * 16 + i15] = (float2){s1, s2};
            }
        }
        __syncthreads();
        if (t < 2) {
            float* invn = ws + (t ? WS_INVNK : WS_INVNQ);
            float* mean = ws + (t ? WS_KMEAN : WS_QMEAN);
            if (tid < 256) {                   // 2 wm x 2 headpair x 64 rows
                int wmf = tid >> 7, p = (tid >> 6) & 1, r = tid & 63;
                float2 aa = rowred[(size_t)(wmf * 4 + 2 * p) * 64 + r];
                float2 bb2 = rowred[(size_t)(wmf * 4 + 2 * p + 1) * 64 + r];
                float s1 = aa.x + bb2.x, s2 = aa.y + bb2.y;
                float iv = rsqrtf(s2), mn = s1 * (1.f / 64.f);
                int n = nbase + wmf * 64 + r;
                int hhq = ((c0 >> 6) + p) * 8 + qg;
                invn[(size_t)hhq * 1024 + n] = iv;
                mean[(size_t)hhq * 1024 + n] = mn;
                lnfin[p * 128 + wmf * 64 + r] = (float2){iv, mn};
            } else if (tid < 384) {            // 2 headpair x 64 cols
                int tt = tid - 256;
                int p = tt >> 6, d = tt & 63;
                int wnn = 2 * p + (d >> 5), loc = d & 31;
                float2 aa = colred[(size_t)(0 * 4 + wnn) * 32 + loc];
                float2 bb2 = colred[(size_t)(1 * 4 + wnn) * 32 + loc];
                int hhq = ((c0 >> 6) + p) * 8 + qg;
                *(float2*)(ws + WS_COLP +
                           (size_t)(((t * 64 + hhq) * 8 + nblk) * 64 + d) * 2) =
                    (float2){aa.x + bb2.x, aa.y + bb2.y};
            }
        }
        __syncthreads();
        if (t == 0) {                          // FQ row-major [hq][n][64]
            u16* fout = (u16*)(ws + WS_FQ) + (size_t)hq * 65536;
#pragma unroll
            for (int fm = 0; fm < 4; fm++)
#pragma unroll
                for (int reg = 0; reg < 4; reg++) {
                    int n = nbase + wm * 64 + fm * 16 + q4 * 4 + reg;
#pragma unroll
                    for (int fn = 0; fn < 2; fn++)
                        fout[(size_t)n * 64 + dwn + fn * 16 + i15] =
                            f2bf(acc[0][fm][fn][reg]);
                }
        } else if (t == 1) {                   // FKTs/FKTc Gram frag
            u16* fs = (u16*)(ws + WS_FKTS) + (size_t)hq * 65536;
            u16* fc = (u16*)(ws + WS_FKTC) + (size_t)hq * 65536;
#pragma unroll
            for (int fn = 0; fn < 2; fn++) {
                int eoff = ((wn & 1) * 2 + fn) * 16384 + i15 * 32;
#pragma unroll
                for (int fm = 0; fm < 4; fm++) {
                    int n0l = wm * 64 + fm * 16 + q4 * 4;
                    int n0 = nbase + n0l;
                    int off = eoff + (n0 >> 5) * 512 + ((n0 >> 3) & 3) * 8 + (n0 & 7);
                    u16x4 vs, vc;
#pragma unroll
                    for (int reg = 0; reg < 4; reg++) {
                        float2 im = lnfin[hp * 128 + n0l + reg];
                        float val = acc[1][fm][fn][reg];
                        vs[reg] = f2bf(val * im.x);
                        vc[reg] = f2bf(val - im.y);
                    }
                    *(u16x4*)(fs + off) = vs;
                    *(u16x4*)(fc + off) = vc;
                }
            }
        } else {                               // FVT Gram frag
            u16* fv = (u16*)(ws + WS_FVT) + (size_t)hq * 65536;
#pragma unroll
            for (int fn = 0; fn < 2; fn++) {
                int doff = ((wn & 1) * 2 + fn) * 16384 + i15 * 32;
#pragma unroll
                for (int fm = 0; fm < 4; fm++) {
                    int n0 = nbase + wm * 64 + fm * 16 + q4 * 4;
                    int off = doff + (n0 >> 5) * 512 + ((n0 >> 3) & 3) * 8 + (n0 & 7);
                    u16x4 v4;
#pragma unroll
                    for (int reg = 0; reg < 4; reg++) v4[reg] = f2bf(acc[2][fm][fn][reg]);
                    *(u16x4*)(fv + off) = v4;
                }
            }
        }
    }
}

// ---------------- K6 (out-proj GEMM): round-10 proven structure ------------
template <int CPX>
__global__ __launch_bounds__(512, 4) void k_gemm_out(
    const u16* __restrict__ A, const u16* __restrict__ B,
    float* __restrict__ out, const float* __restrict__ bias) {
    __shared__ char smem[65536];               // 4 bufs x (A 8K + B 8K)
    int tid = threadIdx.x;
    int wid = tid >> 6, lane = tid & 63;
    int i15 = lane & 15, q4 = lane >> 4;
    int wm = wid >> 2, wn = wid & 3;
    int flat = blockIdx.x + (blockIdx.y << 2);
    int swz = (flat & 7) * CPX + (flat >> 3);
    int c0 = (swz & 3) * 128, m0 = (swz >> 2) * 128;

    floatx4 acc[4][2];
#pragma unroll
    for (int i = 0; i < 4; i++)
#pragma unroll
        for (int j = 0; j < 2; j++) acc[i][j] = (floatx4){0.f, 0.f, 0.f, 0.f};

    const u16* gA = A + (size_t)m0 * 512;
    const u16* gB = B + (size_t)c0 * 512;

    auto stage = [&](int ks, int buf) {
        int o = wid * 1024 + lane * 16;
        int srow = o >> 6, s = (o >> 4) & 3;
        int cch = (s - (srow >> 1)) & 3;
        const u16* ga = gA + (size_t)srow * 512 + ks * 32 + cch * 8;
        const u16* gb = gB + (size_t)srow * 512 + ks * 32 + cch * 8;
        char* la = smem + buf * 16384 + wid * 1024;
        char* lb = smem + buf * 16384 + 8192 + wid * 1024;
        __builtin_amdgcn_global_load_lds(
            (const __attribute__((address_space(1))) void*)ga,
            (__attribute__((address_space(3))) void*)la, 16, 0, 0);
        __builtin_amdgcn_global_load_lds(
            (const __attribute__((address_space(1))) void*)gb,
            (__attribute__((address_space(3))) void*)lb, 16, 0, 0);
    };

    stage(0, 0);
    stage(1, 1);
    stage(2, 2);
    __builtin_amdgcn_sched_barrier(0);
#pragma unroll
    for (int ks = 0; ks < 16; ks++) {
        __builtin_amdgcn_sched_barrier(0);
        if (ks <= 13)      asm volatile("s_waitcnt vmcnt(4)" ::: "memory");
        else if (ks == 14) asm volatile("s_waitcnt vmcnt(2)" ::: "memory");
        else               asm volatile("s_waitcnt vmcnt(0)" ::: "memory");
        __builtin_amdgcn_s_barrier();
        __builtin_amdgcn_sched_barrier(0);
        if (ks + 3 < 16) stage(ks + 3, (ks + 3) & 3);
        __builtin_amdgcn_sched_barrier(0);
        int buf = ks & 3;
        short8 a[4], b[2];
#pragma unroll
        for (int f = 0; f < 4; f++) {
            int ra = wm * 64 + f * 16 + i15;
            int sa = (q4 + (ra >> 1)) & 3;
            a[f] = *(const short8*)(smem + buf * 16384 + ra * 64 + sa * 16);
        }
#pragma unroll
        for (int f = 0; f < 2; f++) {
            int rb = wn * 32 + f * 16 + i15;
            int sb = (q4 + (rb >> 1)) & 3;
            b[f] = *(const short8*)(smem + buf * 16384 + 8192 + rb * 64 + sb * 16);
        }
#pragma unroll
        for (int fm = 0; fm < 4; fm++)
#pragma unroll
            for (int fn = 0; fn < 2; fn++)
                acc[fm][fn] = __builtin_amdgcn_mfma_f32_16x16x32_bf16(
                    a[fm], b[fn], acc[fm][fn], 0, 0, 0);
    }
#pragma unroll
    for (int fm = 0; fm < 4; fm++)
#pragma unroll
        for (int reg = 0; reg < 4; reg++) {
            int gm = m0 + wm * 64 + fm * 16 + q4 * 4 + reg;
#pragma unroll
            for (int fn = 0; fn < 2; fn++) {
                int gc = c0 + wn * 32 + fn * 16 + i15;
                out[(size_t)gm * 512 + gc] = acc[fm][fn][reg] + bias[gc];
            }
        }
}

// ---------------- K3a: parallel COLP reduction -> GSUM[2][8][64][2] --------
__global__ __launch_bounds__(256) void k_gatered(float* __restrict__ ws) {
    int h = blockIdx.x, t = blockIdx.y;
    int tid = threadIdx.x;
    int c = tid & 127, rg = tid >> 7;
    const float* base = ws + WS_COLP + ((size_t)(t * 64 + h * 8) * 8) * 128;
    float s = 0.f;
#pragma unroll 8
    for (int r = rg * 32; r < rg * 32 + 32; r++) s += base[(size_t)r * 128 + c];
    __shared__ float red[2][128];
    red[rg][c] = s;
    __syncthreads();
    if (tid < 128)
        ws[WS_GSUM + ((size_t)t * 8 + h) * 128 + tid] = red[0][tid] + red[1][tid];
}

// ---------------- K3b: gate MLP + variance penalty ----------------
__global__ __launch_bounds__(256) void k_gate(
    const float* __restrict__ pw1, const float* __restrict__ pb1,
    const float* __restrict__ plg, const float* __restrict__ plb,
    const float* __restrict__ pw2, const float* __restrict__ pb2,
    float* __restrict__ ws) {
    __shared__ float w1[128][64];
    __shared__ float gs[2][8][128];
    int tid = threadIdx.x, wid = tid >> 6, lane = tid & 63;
    for (int r = wid; r < 128; r += 4) w1[r][lane] = pw1[r * 64 + lane];
    for (int i = tid; i < 2048; i += 256) ((float*)gs)[i] = ws[WS_GSUM + i];
    __syncthreads();
    if (wid != 0) return;
    float Sq = 0, SSq = 0, Sk = 0, SSk = 0;
#pragma unroll
    for (int h = 0; h < 8; h++) {
        Sq += gs[0][h][lane * 2];  SSq += gs[0][h][lane * 2 + 1];
        Sk += gs[1][h][lane * 2];  SSk += gs[1][h][lane * 2 + 1];
    }
    const float NR = 65536.f;
    float stdq = sqrtf((SSq - Sq * Sq / NR) / (NR - 1.f) + 1e-4f);
    float stdk = sqrtf((SSk - Sk * Sk / NR) / (NR - 1.f) + 1e-4f);
    float vpen = (wsum(fmaxf(1.f - stdq, 0.f)) + wsum(fmaxf(1.f - stdk, 0.f))) * (1.f / 64.f);
    float gammav = plg[lane], betav = plb[lane], w2v = pw2[lane];
    for (int h = 0; h < 8; h++) {
        float y = pb1[lane];
#pragma unroll 8
        for (int i = 0; i < 64; i++) {
            y = fmaf(gs[0][h][i * 2] * (1.f / 8192.f), w1[i][lane], y);
            y = fmaf(gs[1][h][i * 2] * (1.f / 8192.f), w1[64 + i][lane], y);
        }
        float mu = wsum(y) * (1.f / 64.f);
        float dv = y - mu;
        float var = wsum(dv * dv) * (1.f / 64.f);
        float z = dv * rsqrtf(var + 1e-5f) * gammav + betav;
        float r = fmaxf(z, 0.f);
        float sdot = wsum(r * w2v);
        if (lane == 0) {
            float wv = 1.f / (1.f + expf(-(sdot + pb2[0])));
            ws[WS_WGATE + h] = wv / (1.f + vpen);
        }
    }
}

// ------- K4 (MFMA): M,C Gram matrices per hq, K=1024, barrier-free ---------
__global__ __launch_bounds__(256) void k_mc(float* __restrict__ ws) {
    int hq = blockIdx.x;
    int tid = threadIdx.x, wid = tid >> 6, lane = tid & 63;
    int i15 = lane & 15, q4 = lane >> 4;
    int we = wid >> 1, wd = wid & 1;
    const u16* fs = (const u16*)(ws + WS_FKTS) + (size_t)hq * 65536;
    const u16* fc = (const u16*)(ws + WS_FKTC) + (size_t)hq * 65536;
    const u16* fv = (const u16*)(ws + WS_FVT) + (size_t)hq * 65536;
    floatx4 aM[2][2], aC[2][2];
#pragma unroll
    for (int f = 0; f < 2; f++)
#pragma unroll
        for (int g = 0; g < 2; g++) {
            aM[f][g] = (floatx4){0.f, 0.f, 0.f, 0.f};
            aC[f][g] = (floatx4){0.f, 0.f, 0.f, 0.f};
        }
#pragma unroll 8
    for (int ks = 0; ks < 32; ks++) {
        short8 as_[2], ac_[2], b_[2];
#pragma unroll
        for (int f = 0; f < 2; f++) {
            int off = (we * 2 + f) * 16384 + ks * 512 + i15 * 32 + q4 * 8;
            as_[f] = *(const short8*)(fs + off);
            ac_[f] = *(const short8*)(fc + off);
        }
#pragma unroll
        for (int g = 0; g < 2; g++)
            b_[g] = *(const short8*)(fv + (wd * 2 + g) * 16384 + ks * 512 +
                                     i15 * 32 + q4 * 8);
#pragma unroll
        for (int f = 0; f < 2; f++)
#pragma unroll
            for (int g = 0; g < 2; g++) {
                aM[f][g] = __builtin_amdgcn_mfma_f32_16x16x32_bf16(
                    as_[f], b_[g], aM[f][g], 0, 0, 0);
                aC[f][g] = __builtin_amdgcn_mfma_f32_16x16x32_bf16(
                    ac_[f], b_[g], aC[f][g], 0, 0, 0);
            }
    }
    __shared__ float tile[2][64][65];
    __shared__ float cred[4][64];
#pragma unroll
    for (int f = 0; f < 2; f++)
#pragma unroll
        for (int g = 0; g < 2; g++)
#pragma unroll
            for (int reg = 0; reg < 4; reg++) {
                int e = we * 32 + f * 16 + q4 * 4 + reg;
                int d = wd * 32 + g * 16 + i15;
                tile[0][e][d] = aM[f][g][reg];
                tile[1][e][d] = aC[f][g][reg];
            }
    __syncthreads();
    int d = tid & 63, ec = tid >> 6;
    float cp = 0.f;
#pragma unroll
    for (int i = 0; i < 16; i++) cp += tile[1][ec * 16 + i][d];
    cred[ec][d] = cp;
#pragma unroll
    for (int mat = 0; mat < 2; mat++) {
        u16x8 p0, p1;
#pragma unroll
        for (int i = 0; i < 8; i++) {
            p0[i] = f2bf(tile[mat][ec * 16 + i][d]);
            p1[i] = f2bf(tile[mat][ec * 16 + 8 + i][d]);
        }
        u16* dst = (u16*)(ws + (mat ? WS_CTB : WS_MTB)) + (size_t)hq * 4096 + d * 64 + ec * 16;
        *(u16x8*)dst = p0;
        *(u16x8*)(dst + 8) = p1;
    }
    __syncthreads();
    if (tid < 64)
        ws[WS_COLC + (size_t)hq * 64 + tid] =
            cred[0][tid] + cred[1][tid] + cred[2][tid] + cred[3][tid];
}

// ---- K5 (MFMA): out_attn = c1*inv*(fq@M) + c2*(fq@C - qm*colC)  bf16 out ---
__global__ __launch_bounds__(256) void k_apply(float* __restrict__ ws) {
    int nt = blockIdx.x, hq = blockIdx.y;
    int h = hq >> 3, qg = hq & 7;
    __shared__ u16 mt[2][4096];                // swizzled M^T, C^T (8KB each)
    __shared__ float invqm[256][2];
    __shared__ u16 outs[256][66];              // +2 pad
    int tid = threadIdx.x, wid = tid >> 6, lane = tid & 63;
    int i15 = lane & 15, q4 = lane >> 4;
#pragma unroll
    for (int mat = 0; mat < 2; mat++) {
        const u16* src = (const u16*)(ws + (mat ? WS_CTB : WS_MTB)) + (size_t)hq * 4096;
#pragma unroll
        for (int it = 0; it < 2; it++) {
            int i = tid + it * 256;            // 16B chunk id, 512 total
            int d = i >> 3, c8 = i & 7;
            u16x8 v = *(const u16x8*)(src + i * 8);
            int byte = d * 128 + ((c8 * 16) ^ ((d & 7) << 4));
            *(u16x8*)((char*)&mt[mat][0] + byte) = v;
        }
    }
    int R0 = nt * 256;
    invqm[tid][0] = ws[WS_INVNQ + (size_t)hq * 1024 + R0 + tid];
    invqm[tid][1] = ws[WS_QMEAN + (size_t)hq * 1024 + R0 + tid];
    float wv = ws[WS_WGATE + h];
    float c1 = 1.f - wv, c2 = wv * (1.f / 64.f);
    float colc[4];
#pragma unroll
    for (int fn = 0; fn < 4; fn++)
        colc[fn] = ws[WS_COLC + (size_t)hq * 64 + fn * 16 + i15];
    __syncthreads();
    const u16* fq = (const u16*)(ws + WS_FQ) + (size_t)hq * 65536 +
                    (size_t)(R0 + wid * 64) * 64;
    floatx4 aM[4][4], aC[4][4];
#pragma unroll
    for (int i = 0; i < 4; i++)
#pragma unroll
        for (int j = 0; j < 4; j++) {
            aM[i][j] = (floatx4){0.f, 0.f, 0.f, 0.f};
            aC[i][j] = (floatx4){0.f, 0.f, 0.f, 0.f};
        }
#pragma unroll
    for (int ks = 0; ks < 2; ks++) {
        short8 a[4], bM[4], bC[4];
#pragma unroll
        for (int f = 0; f < 4; f++)
            a[f] = *(const short8*)(fq + (size_t)(f * 16 + i15) * 64 + q4 * 8 + ks * 32);
#pragma unroll
        for (int f = 0; f < 4; f++) {
            int col = f * 16 + i15;
            int byte = col * 128 + ((q4 * 16 + ks * 64) ^ ((col & 7) << 4));
            bM[f] = *(const short8*)((char*)&mt[0][0] + byte);
            bC[f] = *(const short8*)((char*)&mt[1][0] + byte);
        }
#pragma unroll
        for (int fm = 0; fm < 4; fm++)
#pragma unroll
            for (int fn = 0; fn < 4; fn++) {
                aM[fm][fn] = __builtin_amdgcn_mfma_f32_16x16x32_bf16(
                    a[fm], bM[fn], aM[fm][fn], 0, 0, 0);
                aC[fm][fn] = __builtin_amdgcn_mfma_f32_16x16x32_bf16(
                    a[fm], bC[fn], aC[fm][fn], 0, 0, 0);
            }
    }
#pragma unroll
    for (int fm = 0; fm < 4; fm++)
#pragma unroll
        for (int reg = 0; reg < 4; reg++) {
            int rloc = wid * 64 + fm * 16 + q4 * 4 + reg;
            float iv = invqm[rloc][0], qmv = invqm[rloc][1];
#pragma unroll
            for (int fn = 0; fn < 4; fn++) {
                float val = c1 * iv * aM[fm][fn][reg] +
                            c2 * (aC[fm][fn][reg] - qmv * colc[fn]);
                outs[rloc][fn * 16 + i15] = f2bf(val);
            }
        }
    __syncthreads();
    u16* oat = (u16*)(ws + WS_OATT);
#pragma unroll
    for (int it = 0; it < 8; it++) {
        int c = tid + it * 256;                // 16B chunk id, 2048 total
        int row = c >> 3, c8 = (c & 7) * 8;
        u16x8 v = *(const u16x8*)&outs[row][c8];
        *(u16x8*)(oat + ((size_t)qg * 1024 + R0 + row) * 512 + h * 64 + c8) = v;
    }
}

// ---------------- host launch ----------------
extern "C" void kernel_launch(void* const* d_in, const int* in_sizes, int n_in,
                              void* d_out, int out_size, void* d_ws, size_t ws_size,
                              hipStream_t stream) {
    (void)in_sizes; (void)n_in; (void)out_size; (void)ws_size;
    const float* q = (const float*)d_in[0];
    const float* k = (const float*)d_in[1];
    const float* v = (const float*)d_in[2];
    const float* ln_g = (const float*)d_in[3];
    const float* ln_b = (const float*)d_in[4];
    const float* w_in = (const float*)d_in[5];
    const float* p_w1 = (const float*)d_in[6];
    const float* p_b1 = (const float*)d_in[7];
    const float* p_ln_g = (const float*)d_in[8];
    const float* p_ln_b = (const float*)d_in[9];
    const float* p_w2 = (const float*)d_in[10];
    const float* p_b2 = (const float*)d_in[11];
    const float* w_out = (const float*)d_in[12];
    const float* b_out = (const float*)d_in[13];
    float* ws = (float*)d_ws;
    float* out = (float*)d_out;

    k_lnstats<<<6144, 256, 0, stream>>>(q, k, v, ws);
    k_prep_t<1><<<dim3(8, 8), 256, 0, stream>>>(w_in, ln_g, (u16*)(ws + WS_WPT), ws + WS_WTF32);
    k_prep_t<0><<<dim3(8, 8), 256, 0, stream>>>(w_out, nullptr, (u16*)(ws + WS_WOT), nullptr);
    k_prep_u<<<128, 256, 0, stream>>>(ln_g, ln_b, ws);
    k_proj<32><<<dim3(4, 64), 512, 0, stream>>>((const u16*)(ws + WS_XBF),
                                                (const u16*)(ws + WS_WPT), ws);
    k_gatered<<<dim3(8, 2), 256, 0, stream>>>(ws);
    k_gate<<<1, 256, 0, stream>>>(p_w1, p_b1, p_ln_g, p_ln_b, p_w2, p_b2, ws);
    k_mc<<<64, 256, 0, stream>>>(ws);
    k_apply<<<dim3(4, 64), 256, 0, stream>>>(ws);
    k_gemm_out<32><<<dim3(4, 64), 512, 0, stream>>>((const u16*)(ws + WS_OATT),
                                                    (const u16*)(ws + WS_WOT), out, b_out);
}